// Round 1
// baseline (521.977 us; speedup 1.0000x reference)
//
#include <hip/hip_runtime.h>
#include <hip/hip_bf16.h>
#include <math.h>

// Problem constants
#define BB    1024
#define INN   1024
#define OUTN  1024
#define NQ    10
#define GG    4
#define DEPTH 4
#define QDIM  1024   // 2^NQ
#define EPSN  1e-9f

// ---------------------------------------------------------------------------
// Kernel 0: xs = x * inp_scale   (elementwise, column-scaled)
// ---------------------------------------------------------------------------
__global__ __launch_bounds__(256) void scale_x_kernel(
    const float* __restrict__ x, const float* __restrict__ sc,
    float* __restrict__ xs)
{
    int i = blockIdx.x * 256 + threadIdx.x;          // float4 index, 262144 total
    float4 v = ((const float4*)x)[i];
    int col4 = i & 255;                               // 256 float4 per row of 1024
    float4 s = ((const float4*)sc)[col4];
    v.x *= s.x; v.y *= s.y; v.z *= s.z; v.w *= s.w;
    ((float4*)xs)[i] = v;
}

// ---------------------------------------------------------------------------
// Kernel 1/5: fp32 SGEMM  C(M,N) = A(M,K) * B(N,K)^T + bias(N)
// 64x64 tile, BK=32, 256 threads, 4x4 per thread
// ---------------------------------------------------------------------------
__global__ __launch_bounds__(256) void sgemm_nt(
    const float* __restrict__ A, const float* __restrict__ Bw,
    const float* __restrict__ bias, float* __restrict__ C,
    int M, int N, int K)
{
    __shared__ float As[32][64];
    __shared__ float Bs[32][64];
    const int tid = threadIdx.x;
    const int m0 = blockIdx.y * 64;
    const int n0 = blockIdx.x * 64;

    const int lrow = tid >> 2;          // 0..63
    const int lkq  = (tid & 3) * 8;     // 0,8,16,24

    const int ty = tid >> 4;            // 0..15
    const int tx = tid & 15;            // 0..15

    float acc[4][4] = {};

    for (int kt = 0; kt < K; kt += 32) {
        // load A tile 64x32
        {
            const float* Ap = A + (size_t)(m0 + lrow) * K + kt + lkq;
            float4 a0 = *(const float4*)Ap;
            float4 a1 = *(const float4*)(Ap + 4);
            As[lkq + 0][lrow] = a0.x; As[lkq + 1][lrow] = a0.y;
            As[lkq + 2][lrow] = a0.z; As[lkq + 3][lrow] = a0.w;
            As[lkq + 4][lrow] = a1.x; As[lkq + 5][lrow] = a1.y;
            As[lkq + 6][lrow] = a1.z; As[lkq + 7][lrow] = a1.w;
        }
        // load B tile 64x32
        {
            const float* Bp = Bw + (size_t)(n0 + lrow) * K + kt + lkq;
            float4 b0 = *(const float4*)Bp;
            float4 b1 = *(const float4*)(Bp + 4);
            Bs[lkq + 0][lrow] = b0.x; Bs[lkq + 1][lrow] = b0.y;
            Bs[lkq + 2][lrow] = b0.z; Bs[lkq + 3][lrow] = b0.w;
            Bs[lkq + 4][lrow] = b1.x; Bs[lkq + 5][lrow] = b1.y;
            Bs[lkq + 6][lrow] = b1.z; Bs[lkq + 7][lrow] = b1.w;
        }
        __syncthreads();
        #pragma unroll
        for (int k = 0; k < 32; ++k) {
            float4 av = *(const float4*)&As[k][ty * 4];
            float4 bv = *(const float4*)&Bs[k][tx * 4];
            acc[0][0] += av.x * bv.x; acc[0][1] += av.x * bv.y;
            acc[0][2] += av.x * bv.z; acc[0][3] += av.x * bv.w;
            acc[1][0] += av.y * bv.x; acc[1][1] += av.y * bv.y;
            acc[1][2] += av.y * bv.z; acc[1][3] += av.y * bv.w;
            acc[2][0] += av.z * bv.x; acc[2][1] += av.z * bv.y;
            acc[2][2] += av.z * bv.z; acc[2][3] += av.z * bv.w;
            acc[3][0] += av.w * bv.x; acc[3][1] += av.w * bv.y;
            acc[3][2] += av.w * bv.z; acc[3][3] += av.w * bv.w;
        }
        __syncthreads();
    }

    float4 bv;
    bv.x = bias[n0 + tx * 4 + 0]; bv.y = bias[n0 + tx * 4 + 1];
    bv.z = bias[n0 + tx * 4 + 2]; bv.w = bias[n0 + tx * 4 + 3];
    #pragma unroll
    for (int i = 0; i < 4; ++i) {
        float4 o;
        o.x = acc[i][0] + bv.x; o.y = acc[i][1] + bv.y;
        o.z = acc[i][2] + bv.z; o.w = acc[i][3] + bv.w;
        *(float4*)&C[(size_t)(m0 + ty * 4 + i) * N + n0 + tx * 4] = o;
    }
}

// ---------------------------------------------------------------------------
// Kernel 2: angles = tanh(xs @ reup_w^T + reup_b) * pi  -> ang[(b*G+g)*NQ+i]
// one block per batch row; wave w handles outputs j = w, w+4, ...
// ---------------------------------------------------------------------------
__global__ __launch_bounds__(256) void reup_kernel(
    const float* __restrict__ xs, const float* __restrict__ W,
    const float* __restrict__ bias, float* __restrict__ ang)
{
    const int b = blockIdx.x;
    const int lane = threadIdx.x & 63;
    const int wv = threadIdx.x >> 6;

    const float* xrow = xs + (size_t)b * INN;
    float xr[16];
    #pragma unroll
    for (int t = 0; t < 16; ++t) xr[t] = xrow[lane + 64 * t];

    for (int j = wv; j < NQ * GG; j += 4) {
        const float* wrow = W + (size_t)j * INN;
        float s = 0.f;
        #pragma unroll
        for (int t = 0; t < 16; ++t) s += xr[t] * wrow[lane + 64 * t];
        #pragma unroll
        for (int off = 32; off; off >>= 1) s += __shfl_xor(s, off, 64);
        if (lane == 0) {
            float a = tanhf(s + bias[j]) * 3.14159265358979323846f;
            int g = j / NQ, i = j % NQ;
            ang[((size_t)b * GG + g) * NQ + i] = a;
        }
    }
}

// ---------------------------------------------------------------------------
// Kernel 3: precompute P_{g,l,i} = Ry(qw1) * Rx(qw0)   (complex 2x2, 8 floats)
// ---------------------------------------------------------------------------
__global__ void prep_P(const float* __restrict__ qw, float* __restrict__ P)
{
    int t = threadIdx.x;
    if (t >= GG * DEPTH * NQ) return;     // t = (g*DEPTH+l)*NQ+i
    const float* q = qw + (size_t)t * 3;
    float c0, s0, c1, s1;
    __sincosf(0.5f * q[0], &s0, &c0);  // use precise versions below instead
    // recompute with precise trig:
    s0 = sinf(0.5f * q[0]); c0 = cosf(0.5f * q[0]);
    s1 = sinf(0.5f * q[1]); c1 = cosf(0.5f * q[1]);
    float* o = P + (size_t)t * 8;
    // P00 = c1*c0 + i s1*s0 ; P01 = -s1*c0 - i c1*s0
    // P10 = s1*c0 - i c1*s0 ; P11 =  c1*c0 - i s1*s0
    o[0] = c1 * c0;  o[1] = s1 * s0;
    o[2] = -s1 * c0; o[3] = -c1 * s0;
    o[4] = s1 * c0;  o[5] = -c1 * s0;
    o[6] = c1 * c0;  o[7] = -s1 * s0;
}

// ---------------------------------------------------------------------------
// Kernel 4: quantum statevector simulation. One 256-thread block per state.
// State (1024 complex) in LDS. Per layer: 10 fused 1q gates + fused CNOT perm.
// ---------------------------------------------------------------------------
__global__ __launch_bounds__(256) void quantum_kernel(
    const float* __restrict__ xq, const float* __restrict__ ang,
    const float* __restrict__ P, const float* __restrict__ qw,
    const float* __restrict__ us, const float* __restrict__ mw,
    float* __restrict__ probs)
{
    __shared__ float sRe[QDIM];
    __shared__ float sIm[QDIM];
    __shared__ float mat[NQ][8];
    __shared__ float red[4];

    const int tid = threadIdx.x;
    const int wid = blockIdx.x;          // b*G+g
    const int g = wid & 3;

    // ---- load row, compute norm, init state ----
    float4 v = ((const float4*)(xq + (size_t)wid * QDIM))[tid];
    float ss = v.x * v.x + v.y * v.y + v.z * v.z + v.w * v.w;
    #pragma unroll
    for (int off = 32; off; off >>= 1) ss += __shfl_xor(ss, off, 64);
    if ((tid & 63) == 0) red[tid >> 6] = ss;
    __syncthreads();
    float tot = red[0] + red[1] + red[2] + red[3];
    float scl = 1.f / (sqrtf(tot) + EPSN);
    {
        int j = tid * 4;
        sRe[j + 0] = v.x * scl; sRe[j + 1] = v.y * scl;
        sRe[j + 2] = v.z * scl; sRe[j + 3] = v.w * scl;
        sIm[j + 0] = 0.f; sIm[j + 1] = 0.f; sIm[j + 2] = 0.f; sIm[j + 3] = 0.f;
    }

    // fused general 2x2 complex gate pass on wire i (matrix in mat[i])
    auto gate = [&](int i) {
        const int sh = 9 - i;
        const float m0r = mat[i][0], m0i = mat[i][1];
        const float m1r = mat[i][2], m1i = mat[i][3];
        const float m2r = mat[i][4], m2i = mat[i][5];
        const float m3r = mat[i][6], m3i = mat[i][7];
        #pragma unroll
        for (int r = 0; r < 2; ++r) {
            int p = tid + r * 256;
            int lo = p & ((1 << sh) - 1);
            int i0 = ((p >> sh) << (sh + 1)) | lo;
            int i1 = i0 + (1 << sh);
            float a0r = sRe[i0], a0i = sIm[i0];
            float a1r = sRe[i1], a1i = sIm[i1];
            sRe[i0] = m0r * a0r - m0i * a0i + m1r * a1r - m1i * a1i;
            sIm[i0] = m0r * a0i + m0i * a0r + m1r * a1i + m1i * a1r;
            sRe[i1] = m2r * a0r - m2i * a0i + m3r * a1r - m3i * a1i;
            sIm[i1] = m2r * a0i + m2i * a0r + m3r * a1i + m3i * a1r;
        }
        __syncthreads();
    };

    float carry = 0.f;
    const float myang = (tid < NQ) ? ang[(size_t)wid * NQ + tid] : 0.f;

    for (int l = 0; l < DEPTH; ++l) {
        // build fused gate matrices M = P * Ry(beta), beta = ang*us + carry
        if (tid < NQ) {
            int idx = (g * DEPTH + l) * NQ + tid;
            float beta = myang * us[idx] + carry;
            carry = qw[(size_t)idx * 3 + 2];
            float cb = cosf(0.5f * beta), sb = sinf(0.5f * beta);
            const float* p = P + (size_t)idx * 8;
            float* m = mat[tid];
            m[0] = p[0] * cb + p[2] * sb;  m[1] = p[1] * cb + p[3] * sb;
            m[2] = p[2] * cb - p[0] * sb;  m[3] = p[3] * cb - p[1] * sb;
            m[4] = p[4] * cb + p[6] * sb;  m[5] = p[5] * cb + p[7] * sb;
            m[6] = p[6] * cb - p[4] * sb;  m[7] = p[7] * cb - p[5] * sb;
        }
        __syncthreads();
        for (int i = 0; i < NQ; ++i) gate(i);

        // fused CNOT chain: cnot(0,1) cnot(1,2) ... cnot(9,0) as one permutation
        {
            float tr[4], ti[4];
            #pragma unroll
            for (int r = 0; r < 4; ++r) {
                int j = tid + (r << 8);
                int k = j;
                #pragma unroll
                for (int ii = NQ - 1; ii >= 0; --ii) {
                    int bc = 9 - ii;
                    int bt = (ii == NQ - 1) ? 9 : (8 - ii);
                    k ^= ((k >> bc) & 1) << bt;
                }
                tr[r] = sRe[k]; ti[r] = sIm[k];
            }
            __syncthreads();
            #pragma unroll
            for (int r = 0; r < 4; ++r) {
                int j = tid + (r << 8);
                sRe[j] = tr[r]; sIm[j] = ti[r];
            }
            __syncthreads();
        }
    }

    // final measurement gates: F = U3(mw) * Ry(carry)
    if (tid < NQ) {
        const float* q = mw + ((size_t)g * NQ + tid) * 3;
        float th = q[0], ph = q[1], lm = q[2];
        float c = cosf(0.5f * th), s = sinf(0.5f * th);
        float epr = cosf(ph), epi = sinf(ph);
        float elr = cosf(lm), eli = sinf(lm);
        // u3: m00=(c,0); m01=-el*s; m10=ep*s; m11=ep*el*c
        float u0r = c,               u0i = 0.f;
        float u1r = -elr * s,        u1i = -eli * s;
        float u2r = epr * s,         u2i = epi * s;
        float u3r = (epr * elr - epi * eli) * c;
        float u3i = (epr * eli + epi * elr) * c;
        float cc = cosf(0.5f * carry), scr = sinf(0.5f * carry);
        float* m = mat[tid];
        m[0] = u0r * cc + u1r * scr;  m[1] = u0i * cc + u1i * scr;
        m[2] = u1r * cc - u0r * scr;  m[3] = u1i * cc - u0i * scr;
        m[4] = u2r * cc + u3r * scr;  m[5] = u2i * cc + u3i * scr;
        m[6] = u3r * cc - u2r * scr;  m[7] = u3i * cc - u2i * scr;
    }
    __syncthreads();
    for (int i = 0; i < NQ; ++i) gate(i);

    // probs
    {
        int j = tid * 4;
        float4 o;
        o.x = sRe[j + 0] * sRe[j + 0] + sIm[j + 0] * sIm[j + 0];
        o.y = sRe[j + 1] * sRe[j + 1] + sIm[j + 1] * sIm[j + 1];
        o.z = sRe[j + 2] * sRe[j + 2] + sIm[j + 2] * sIm[j + 2];
        o.w = sRe[j + 3] * sRe[j + 3] + sIm[j + 3] * sIm[j + 3];
        ((float4*)(probs + (size_t)wid * QDIM))[tid] = o;
    }
}

// ---------------------------------------------------------------------------
extern "C" void kernel_launch(void* const* d_in, const int* in_sizes, int n_in,
                              void* d_out, int out_size, void* d_ws, size_t ws_size,
                              hipStream_t stream)
{
    const float* x          = (const float*)d_in[0];
    const float* inp_scale  = (const float*)d_in[1];
    const float* proj_in_w  = (const float*)d_in[2];
    const float* proj_in_b  = (const float*)d_in[3];
    const float* reup_w     = (const float*)d_in[4];
    const float* reup_b     = (const float*)d_in[5];
    const float* q_weights  = (const float*)d_in[6];
    const float* upl_scales = (const float*)d_in[7];
    const float* meas_w     = (const float*)d_in[8];
    const float* proj_out_w = (const float*)d_in[9];
    const float* proj_out_b = (const float*)d_in[10];
    float* out = (float*)d_out;

    char* ws = (char*)d_ws;
    float* xq_raw = (float*)(ws);                                   // 16 MB
    float* probs  = (float*)(ws + (size_t)(16 << 20));              // 16 MB
    float* xs     = (float*)(ws + (size_t)(32 << 20));              // 4 MB
    float* angb   = (float*)(ws + (size_t)(36 << 20));              // 160 KB
    float* Pm     = (float*)(ws + (size_t)(36 << 20) + (256 << 10));// 5 KB

    scale_x_kernel<<<1024, 256, 0, stream>>>(x, inp_scale, xs);
    sgemm_nt<<<dim3(64, 16), 256, 0, stream>>>(xs, proj_in_w, proj_in_b, xq_raw,
                                               BB, GG * QDIM, INN);
    reup_kernel<<<BB, 256, 0, stream>>>(xs, reup_w, reup_b, angb);
    prep_P<<<1, 256, 0, stream>>>(q_weights, Pm);
    quantum_kernel<<<BB * GG, 256, 0, stream>>>(xq_raw, angb, Pm, q_weights,
                                                upl_scales, meas_w, probs);
    sgemm_nt<<<dim3(16, 16), 256, 0, stream>>>(probs, proj_out_w, proj_out_b, out,
                                               BB, OUTN, GG * QDIM);
}

// Round 3
// 283.859 us; speedup vs baseline: 1.8389x; 1.8389x over previous
//
#include <hip/hip_runtime.h>
#include <hip/hip_bf16.h>
#include <math.h>

// Problem constants
#define BB    1024
#define INN   1024
#define OUTN  1024
#define NQ    10
#define GG    4
#define DEPTH 4
#define QDIM  1024   // 2^NQ
#define EPSN  1e-9f

typedef short  bf16x8 __attribute__((ext_vector_type(8)));
typedef float  f32x4  __attribute__((ext_vector_type(4)));

#define GLOAD_LDS16(gp, lp) __builtin_amdgcn_global_load_lds( \
    (__attribute__((address_space(1))) const void*)(gp),      \
    (__attribute__((address_space(3))) void*)(lp), 16, 0, 0)

__device__ __forceinline__ unsigned short f2bf(float f) {
    unsigned int u = __float_as_uint(f);
    u = (u + 0x7FFFu + ((u >> 16) & 1u)) >> 16;   // RNE, finite inputs
    return (unsigned short)u;
}

// ---------------------------------------------------------------------------
// xsb = bf16(x * inp_scale)   (8 elems/thread)
// ---------------------------------------------------------------------------
__global__ __launch_bounds__(256) void scale_cast_kernel(
    const float* __restrict__ x, const float* __restrict__ sc,
    unsigned short* __restrict__ xsb)
{
    int i = blockIdx.x * 256 + threadIdx.x;          // 8-elem index
    float4 a = ((const float4*)x)[2 * i];
    float4 b = ((const float4*)x)[2 * i + 1];
    int c4 = (2 * i) & 255;                           // 256 float4 per 1024-row
    float4 s0 = ((const float4*)sc)[c4];
    float4 s1 = ((const float4*)sc)[c4 + 1];
    ushort4 o0, o1;
    o0.x = f2bf(a.x * s0.x); o0.y = f2bf(a.y * s0.y);
    o0.z = f2bf(a.z * s0.z); o0.w = f2bf(a.w * s0.w);
    o1.x = f2bf(b.x * s1.x); o1.y = f2bf(b.y * s1.y);
    o1.z = f2bf(b.z * s1.z); o1.w = f2bf(b.w * s1.w);
    ((ushort4*)xsb)[2 * i]     = o0;
    ((ushort4*)xsb)[2 * i + 1] = o1;
}

// ---------------------------------------------------------------------------
// wb = bf16(w)   (8 elems/thread)
// ---------------------------------------------------------------------------
__global__ __launch_bounds__(256) void cast_w_kernel(
    const float* __restrict__ w, unsigned short* __restrict__ wb)
{
    int i = blockIdx.x * 256 + threadIdx.x;
    float4 a = ((const float4*)w)[2 * i];
    float4 b = ((const float4*)w)[2 * i + 1];
    ushort4 o0, o1;
    o0.x = f2bf(a.x); o0.y = f2bf(a.y); o0.z = f2bf(a.z); o0.w = f2bf(a.w);
    o1.x = f2bf(b.x); o1.y = f2bf(b.y); o1.z = f2bf(b.z); o1.w = f2bf(b.w);
    ((ushort4*)wb)[2 * i]     = o0;
    ((ushort4*)wb)[2 * i + 1] = o1;
}

// ---------------------------------------------------------------------------
// bf16 MFMA GEMM: C(M,N) = A(M,K) * W(N,K)^T + bias(N), fp32 out.
// 256 threads = 4 waves (2x2). Wave tile (BM/2)x(BN/2). 16x16x32 MFMA.
// global_load_lds width-16 staging, single-buffered (m97 structure).
// ---------------------------------------------------------------------------
template<int BM, int BN, int BK>
__global__ __launch_bounds__(256) void gemm_bt_bf16(
    const unsigned short* __restrict__ A, const unsigned short* __restrict__ Bw,
    const float* __restrict__ bias, float* __restrict__ C,
    int M, int N, int K)
{
    constexpr int WM = BM / 2, WN = BN / 2;
    constexpr int FM = WM / 16, FN = WN / 16;
    constexpr int KS = BK / 32;
    constexpr int NISS = (BM * BK) / 2048;   // 16B x 256 threads = 4096B/issue

    __shared__ unsigned short As[BM * BK];
    __shared__ unsigned short Bs[BN * BK];

    const int tid  = threadIdx.x;
    const int lane = tid & 63;
    const int wave = tid >> 6;
    const int wm = wave >> 1, wn = wave & 1;
    const int m0 = blockIdx.y * BM;
    const int n0 = blockIdx.x * BN;

    const int cl = lane & 15;      // fragment col (C) / row-sel (A,B)
    const int rh = lane >> 4;      // k-octet selector

    f32x4 acc[FM][FN];
    #pragma unroll
    for (int i = 0; i < FM; ++i)
        #pragma unroll
        for (int j = 0; j < FN; ++j)
            acc[i][j] = (f32x4){0.f, 0.f, 0.f, 0.f};

    for (int kt = 0; kt < K; kt += BK) {
        #pragma unroll
        for (int q = 0; q < NISS; ++q) {
            int eo  = q * 2048 + tid * 8;
            int row = eo / BK, col = eo % BK;
            const unsigned short* ga = A  + (size_t)(m0 + row) * K + kt + col;
            GLOAD_LDS16(ga, &As[eo]);
            const unsigned short* gb = Bw + (size_t)(n0 + row) * K + kt + col;
            GLOAD_LDS16(gb, &Bs[eo]);
        }
        __syncthreads();

        #pragma unroll
        for (int ks = 0; ks < KS; ++ks) {
            bf16x8 af[FM], bfr[FN];
            #pragma unroll
            for (int mi = 0; mi < FM; ++mi)
                af[mi] = *(const bf16x8*)&As[(wm * WM + mi * 16 + cl) * BK + ks * 32 + rh * 8];
            #pragma unroll
            for (int ni = 0; ni < FN; ++ni)
                bfr[ni] = *(const bf16x8*)&Bs[(wn * WN + ni * 16 + cl) * BK + ks * 32 + rh * 8];
            #pragma unroll
            for (int mi = 0; mi < FM; ++mi)
                #pragma unroll
                for (int ni = 0; ni < FN; ++ni)
                    acc[mi][ni] = __builtin_amdgcn_mfma_f32_16x16x32_bf16(
                        af[mi], bfr[ni], acc[mi][ni], 0, 0, 0);
        }
        __syncthreads();
    }

    // epilogue: C/D layout col=lane&15, row=(lane>>4)*4+j  [m89/m91 verified]
    #pragma unroll
    for (int mi = 0; mi < FM; ++mi) {
        #pragma unroll
        for (int ni = 0; ni < FN; ++ni) {
            int gm = m0 + wm * WM + mi * 16 + rh * 4;
            int gn = n0 + wn * WN + ni * 16 + cl;
            float bsv = bias[gn];
            #pragma unroll
            for (int j = 0; j < 4; ++j)
                C[(size_t)(gm + j) * N + gn] = acc[mi][ni][j] + bsv;
        }
    }
}

// ---------------------------------------------------------------------------
// angles = tanh((x*sc) @ reup_w^T + reup_b) * pi
// ---------------------------------------------------------------------------
__global__ __launch_bounds__(256) void reup_kernel(
    const float* __restrict__ x, const float* __restrict__ sc,
    const float* __restrict__ W, const float* __restrict__ bias,
    float* __restrict__ ang)
{
    const int b = blockIdx.x;
    const int lane = threadIdx.x & 63;
    const int wv = threadIdx.x >> 6;

    const float* xrow = x + (size_t)b * INN;
    float xr[16];
    #pragma unroll
    for (int t = 0; t < 16; ++t) xr[t] = xrow[lane + 64 * t] * sc[lane + 64 * t];

    for (int j = wv; j < NQ * GG; j += 4) {
        const float* wrow = W + (size_t)j * INN;
        float s = 0.f;
        #pragma unroll
        for (int t = 0; t < 16; ++t) s += xr[t] * wrow[lane + 64 * t];
        #pragma unroll
        for (int off = 32; off; off >>= 1) s += __shfl_xor(s, off, 64);
        if (lane == 0) {
            float a = tanhf(s + bias[j]) * 3.14159265358979323846f;
            int g = j / NQ, i = j % NQ;
            ang[((size_t)b * GG + g) * NQ + i] = a;
        }
    }
}

// ---------------------------------------------------------------------------
// P_{g,l,i} = Ry(qw1) * Rx(qw0)   (complex 2x2, 8 floats)
// ---------------------------------------------------------------------------
__global__ void prep_P(const float* __restrict__ qw, float* __restrict__ P)
{
    int t = threadIdx.x;
    if (t >= GG * DEPTH * NQ) return;     // t = (g*DEPTH+l)*NQ+i
    const float* q = qw + (size_t)t * 3;
    float s0 = sinf(0.5f * q[0]), c0 = cosf(0.5f * q[0]);
    float s1 = sinf(0.5f * q[1]), c1 = cosf(0.5f * q[1]);
    float* o = P + (size_t)t * 8;
    o[0] = c1 * c0;  o[1] = s1 * s0;
    o[2] = -s1 * c0; o[3] = -c1 * s0;
    o[4] = s1 * c0;  o[5] = -c1 * s0;
    o[6] = c1 * c0;  o[7] = -s1 * s0;
}

// ---------------------------------------------------------------------------
// Quantum statevector sim. One 256-thread block per (b,g) state.
// Outputs probs as bf16.
// ---------------------------------------------------------------------------
__global__ __launch_bounds__(256) void quantum_kernel(
    const float* __restrict__ xq, const float* __restrict__ ang,
    const float* __restrict__ P, const float* __restrict__ qw,
    const float* __restrict__ us, const float* __restrict__ mw,
    unsigned short* __restrict__ probs)
{
    __shared__ float sRe[QDIM];
    __shared__ float sIm[QDIM];
    __shared__ float mat[NQ][8];
    __shared__ float red[4];

    const int tid = threadIdx.x;
    const int wid = blockIdx.x;          // b*G+g
    const int g = wid & 3;

    float4 v = ((const float4*)(xq + (size_t)wid * QDIM))[tid];
    float ss = v.x * v.x + v.y * v.y + v.z * v.z + v.w * v.w;
    #pragma unroll
    for (int off = 32; off; off >>= 1) ss += __shfl_xor(ss, off, 64);
    if ((tid & 63) == 0) red[tid >> 6] = ss;
    __syncthreads();
    float tot = red[0] + red[1] + red[2] + red[3];
    float scl = 1.f / (sqrtf(tot) + EPSN);
    {
        int j = tid * 4;
        sRe[j + 0] = v.x * scl; sRe[j + 1] = v.y * scl;
        sRe[j + 2] = v.z * scl; sRe[j + 3] = v.w * scl;
        sIm[j + 0] = 0.f; sIm[j + 1] = 0.f; sIm[j + 2] = 0.f; sIm[j + 3] = 0.f;
    }

    auto gate = [&](int i) {
        const int sh = 9 - i;
        const float m0r = mat[i][0], m0i = mat[i][1];
        const float m1r = mat[i][2], m1i = mat[i][3];
        const float m2r = mat[i][4], m2i = mat[i][5];
        const float m3r = mat[i][6], m3i = mat[i][7];
        #pragma unroll
        for (int r = 0; r < 2; ++r) {
            int p = tid + r * 256;
            int lo = p & ((1 << sh) - 1);
            int i0 = ((p >> sh) << (sh + 1)) | lo;
            int i1 = i0 + (1 << sh);
            float a0r = sRe[i0], a0i = sIm[i0];
            float a1r = sRe[i1], a1i = sIm[i1];
            sRe[i0] = m0r * a0r - m0i * a0i + m1r * a1r - m1i * a1i;
            sIm[i0] = m0r * a0i + m0i * a0r + m1r * a1i + m1i * a1r;
            sRe[i1] = m2r * a0r - m2i * a0i + m3r * a1r - m3i * a1i;
            sIm[i1] = m2r * a0i + m2i * a0r + m3r * a1i + m3i * a1r;
        }
        __syncthreads();
    };

    float carry = 0.f;
    const float myang = (tid < NQ) ? ang[(size_t)wid * NQ + tid] : 0.f;

    for (int l = 0; l < DEPTH; ++l) {
        if (tid < NQ) {
            int idx = (g * DEPTH + l) * NQ + tid;
            float beta = myang * us[idx] + carry;
            carry = qw[(size_t)idx * 3 + 2];
            float cb = cosf(0.5f * beta), sb = sinf(0.5f * beta);
            const float* p = P + (size_t)idx * 8;
            float* m = mat[tid];
            m[0] = p[0] * cb + p[2] * sb;  m[1] = p[1] * cb + p[3] * sb;
            m[2] = p[2] * cb - p[0] * sb;  m[3] = p[3] * cb - p[1] * sb;
            m[4] = p[4] * cb + p[6] * sb;  m[5] = p[5] * cb + p[7] * sb;
            m[6] = p[6] * cb - p[4] * sb;  m[7] = p[7] * cb - p[5] * sb;
        }
        __syncthreads();
        for (int i = 0; i < NQ; ++i) gate(i);

        // fused CNOT chain as one permutation
        {
            float tr[4], ti[4];
            #pragma unroll
            for (int r = 0; r < 4; ++r) {
                int j = tid + (r << 8);
                int k = j;
                #pragma unroll
                for (int ii = NQ - 1; ii >= 0; --ii) {
                    int bc = 9 - ii;
                    int bt = (ii == NQ - 1) ? 9 : (8 - ii);
                    k ^= ((k >> bc) & 1) << bt;
                }
                tr[r] = sRe[k]; ti[r] = sIm[k];
            }
            __syncthreads();
            #pragma unroll
            for (int r = 0; r < 4; ++r) {
                int j = tid + (r << 8);
                sRe[j] = tr[r]; sIm[j] = ti[r];
            }
            __syncthreads();
        }
    }

    // final measurement gates: F = U3(mw) * Ry(carry)
    if (tid < NQ) {
        const float* q = mw + ((size_t)g * NQ + tid) * 3;
        float th = q[0], ph = q[1], lm = q[2];
        float c = cosf(0.5f * th), s = sinf(0.5f * th);
        float epr = cosf(ph), epi = sinf(ph);
        float elr = cosf(lm), eli = sinf(lm);
        float u0r = c,               u0i = 0.f;
        float u1r = -elr * s,        u1i = -eli * s;
        float u2r = epr * s,         u2i = epi * s;
        float u3r = (epr * elr - epi * eli) * c;
        float u3i = (epr * eli + epi * elr) * c;
        float cc = cosf(0.5f * carry), scr = sinf(0.5f * carry);
        float* m = mat[tid];
        m[0] = u0r * cc + u1r * scr;  m[1] = u0i * cc + u1i * scr;
        m[2] = u1r * cc - u0r * scr;  m[3] = u1i * cc - u0i * scr;
        m[4] = u2r * cc + u3r * scr;  m[5] = u2i * cc + u3i * scr;
        m[6] = u3r * cc - u2r * scr;  m[7] = u3i * cc - u2i * scr;
    }
    __syncthreads();
    for (int i = 0; i < NQ; ++i) gate(i);

    {
        int j = tid * 4;
        ushort4 o;
        o.x = f2bf(sRe[j + 0] * sRe[j + 0] + sIm[j + 0] * sIm[j + 0]);
        o.y = f2bf(sRe[j + 1] * sRe[j + 1] + sIm[j + 1] * sIm[j + 1]);
        o.z = f2bf(sRe[j + 2] * sRe[j + 2] + sIm[j + 2] * sIm[j + 2]);
        o.w = f2bf(sRe[j + 3] * sRe[j + 3] + sIm[j + 3] * sIm[j + 3]);
        ((ushort4*)(probs + (size_t)wid * QDIM))[tid] = o;
    }
}

// ---------------------------------------------------------------------------
extern "C" void kernel_launch(void* const* d_in, const int* in_sizes, int n_in,
                              void* d_out, int out_size, void* d_ws, size_t ws_size,
                              hipStream_t stream)
{
    const float* x          = (const float*)d_in[0];
    const float* inp_scale  = (const float*)d_in[1];
    const float* proj_in_w  = (const float*)d_in[2];
    const float* proj_in_b  = (const float*)d_in[3];
    const float* reup_w     = (const float*)d_in[4];
    const float* reup_b     = (const float*)d_in[5];
    const float* q_weights  = (const float*)d_in[6];
    const float* upl_scales = (const float*)d_in[7];
    const float* meas_w     = (const float*)d_in[8];
    const float* proj_out_w = (const float*)d_in[9];
    const float* proj_out_b = (const float*)d_in[10];
    float* out = (float*)d_out;

    char* ws = (char*)d_ws;
    float*          xq_raw = (float*)ws;                                  // 16 MB
    unsigned short* probsb = (unsigned short*)(ws + ((size_t)16 << 20));  // 8 MB
    unsigned short* wb     = (unsigned short*)(ws + ((size_t)24 << 20));  // 8 MB (reused)
    unsigned short* xsb    = (unsigned short*)(ws + ((size_t)32 << 20));  // 2 MB
    float*          angb   = (float*)(ws + ((size_t)34 << 20));           // 160 KB
    float*          Pm     = (float*)(ws + ((size_t)34 << 20) + (256 << 10)); // 5 KB

    // xsb = bf16(x * inp_scale)
    scale_cast_kernel<<<512, 256, 0, stream>>>(x, inp_scale, xsb);
    // wb = bf16(proj_in_w)
    cast_w_kernel<<<2048, 256, 0, stream>>>(proj_in_w, wb);
    // xq = xsb @ wb^T + b   (1024 x 4096 x 1024)
    gemm_bt_bf16<128, 128, 32><<<dim3(32, 8), 256, 0, stream>>>(
        xsb, wb, proj_in_b, xq_raw, BB, GG * QDIM, INN);
    // angles
    reup_kernel<<<BB, 256, 0, stream>>>(x, inp_scale, reup_w, reup_b, angb);
    prep_P<<<1, 256, 0, stream>>>(q_weights, Pm);
    // quantum sim -> probs (bf16)
    quantum_kernel<<<BB * GG, 256, 0, stream>>>(xq_raw, angb, Pm, q_weights,
                                                upl_scales, meas_w, probsb);
    // wb = bf16(proj_out_w)
    cast_w_kernel<<<2048, 256, 0, stream>>>(proj_out_w, wb);
    // out = probs @ wb^T + b   (1024 x 1024 x 4096)
    gemm_bt_bf16<64, 64, 64><<<dim3(16, 16), 256, 0, stream>>>(
        probsb, wb, proj_out_b, out, BB, OUTN, GG * QDIM);
}

// Round 4
// 256.762 us; speedup vs baseline: 2.0329x; 1.1055x over previous
//
#include <hip/hip_runtime.h>
#include <hip/hip_bf16.h>
#include <math.h>

// Problem constants
#define BB    1024
#define INN   1024
#define OUTN  1024
#define NQ    10
#define GG    4
#define DEPTH 4
#define QDIM  1024   // 2^NQ
#define EPSN  1e-9f

typedef short  bf16x8 __attribute__((ext_vector_type(8)));
typedef float  f32x4  __attribute__((ext_vector_type(4)));

#define GLOAD_LDS16(gp, lp) __builtin_amdgcn_global_load_lds( \
    (__attribute__((address_space(1))) const void*)(gp),      \
    (__attribute__((address_space(3))) void*)(lp), 16, 0, 0)

__device__ __forceinline__ unsigned short f2bf(float f) {
    unsigned int u = __float_as_uint(f);
    u = (u + 0x7FFFu + ((u >> 16) & 1u)) >> 16;   // RNE, finite inputs
    return (unsigned short)u;
}
__device__ __forceinline__ float bf2f(unsigned short u) {
    return __uint_as_float(((unsigned int)u) << 16);
}

// ---------------------------------------------------------------------------
// Fused prep: [0,512): xsb = bf16(x*sc); [512,2560): wb1 = bf16(proj_in_w);
// [2560,4608): wb2 = bf16(proj_out_w); [4608,5632): reup angles.
// ---------------------------------------------------------------------------
__global__ __launch_bounds__(256) void prep_kernel(
    const float* __restrict__ x, const float* __restrict__ sc,
    const float* __restrict__ piw, const float* __restrict__ pow_,
    const float* __restrict__ rw, const float* __restrict__ rb,
    unsigned short* __restrict__ xsb, unsigned short* __restrict__ wb1,
    unsigned short* __restrict__ wb2, float* __restrict__ ang)
{
    const int bid = blockIdx.x;
    if (bid < 4608) {
        const float* src; unsigned short* dst; int i; bool scale = false;
        if (bid < 512)        { src = x;    dst = xsb; i = bid * 256 + threadIdx.x; scale = true; }
        else if (bid < 2560)  { src = piw;  dst = wb1; i = (bid - 512) * 256 + threadIdx.x; }
        else                  { src = pow_; dst = wb2; i = (bid - 2560) * 256 + threadIdx.x; }
        float4 a = ((const float4*)src)[2 * i];
        float4 b = ((const float4*)src)[2 * i + 1];
        if (scale) {
            int c4 = (2 * i) & 255;
            float4 s0 = ((const float4*)sc)[c4];
            float4 s1 = ((const float4*)sc)[c4 + 1];
            a.x *= s0.x; a.y *= s0.y; a.z *= s0.z; a.w *= s0.w;
            b.x *= s1.x; b.y *= s1.y; b.z *= s1.z; b.w *= s1.w;
        }
        ushort4 o0, o1;
        o0.x = f2bf(a.x); o0.y = f2bf(a.y); o0.z = f2bf(a.z); o0.w = f2bf(a.w);
        o1.x = f2bf(b.x); o1.y = f2bf(b.y); o1.z = f2bf(b.z); o1.w = f2bf(b.w);
        ((ushort4*)dst)[2 * i]     = o0;
        ((ushort4*)dst)[2 * i + 1] = o1;
    } else {
        // reup: one block per batch row
        const int b = bid - 4608;
        const int lane = threadIdx.x & 63;
        const int wv = threadIdx.x >> 6;
        const float* xrow = x + (size_t)b * INN;
        float xr[16];
        #pragma unroll
        for (int t = 0; t < 16; ++t) xr[t] = xrow[lane + 64 * t] * sc[lane + 64 * t];
        for (int j = wv; j < NQ * GG; j += 4) {
            const float* wrow = rw + (size_t)j * INN;
            float s = 0.f;
            #pragma unroll
            for (int t = 0; t < 16; ++t) s += xr[t] * wrow[lane + 64 * t];
            #pragma unroll
            for (int off = 32; off; off >>= 1) s += __shfl_xor(s, off, 64);
            if (lane == 0) {
                float a = tanhf(s + rb[j]) * 3.14159265358979323846f;
                int g = j / NQ, i = j % NQ;
                ang[((size_t)b * GG + g) * NQ + i] = a;
            }
        }
    }
}

// ---------------------------------------------------------------------------
// bf16 MFMA GEMM: C(M,N) = A(M,K) * W(N,K)^T + bias(N).
// 256 threads = 4 waves (2x2). OUTBF: bf16 output, else fp32.
// ---------------------------------------------------------------------------
template<int BM, int BN, int BK, bool OUTBF>
__global__ __launch_bounds__(256) void gemm_bt_bf16(
    const unsigned short* __restrict__ A, const unsigned short* __restrict__ Bw,
    const float* __restrict__ bias, void* __restrict__ Cv,
    int M, int N, int K)
{
    constexpr int WM = BM / 2, WN = BN / 2;
    constexpr int FM = WM / 16, FN = WN / 16;
    constexpr int KS = BK / 32;
    constexpr int NA = (BM * BK) / 2048;
    constexpr int NB = (BN * BK) / 2048;

    __shared__ unsigned short As[BM * BK];
    __shared__ unsigned short Bs[BN * BK];

    const int tid  = threadIdx.x;
    const int lane = tid & 63;
    const int wave = tid >> 6;
    const int wm = wave >> 1, wn = wave & 1;
    const int m0 = blockIdx.y * BM;
    const int n0 = blockIdx.x * BN;

    const int cl = lane & 15;
    const int rh = lane >> 4;

    f32x4 acc[FM][FN];
    #pragma unroll
    for (int i = 0; i < FM; ++i)
        #pragma unroll
        for (int j = 0; j < FN; ++j)
            acc[i][j] = (f32x4){0.f, 0.f, 0.f, 0.f};

    for (int kt = 0; kt < K; kt += BK) {
        #pragma unroll
        for (int q = 0; q < NA; ++q) {
            int eo  = q * 2048 + tid * 8;
            int row = eo / BK, col = eo % BK;
            GLOAD_LDS16(A + (size_t)(m0 + row) * K + kt + col, &As[eo]);
        }
        #pragma unroll
        for (int q = 0; q < NB; ++q) {
            int eo  = q * 2048 + tid * 8;
            int row = eo / BK, col = eo % BK;
            GLOAD_LDS16(Bw + (size_t)(n0 + row) * K + kt + col, &Bs[eo]);
        }
        __syncthreads();

        #pragma unroll
        for (int ks = 0; ks < KS; ++ks) {
            bf16x8 af[FM], bfr[FN];
            #pragma unroll
            for (int mi = 0; mi < FM; ++mi)
                af[mi] = *(const bf16x8*)&As[(wm * WM + mi * 16 + cl) * BK + ks * 32 + rh * 8];
            #pragma unroll
            for (int ni = 0; ni < FN; ++ni)
                bfr[ni] = *(const bf16x8*)&Bs[(wn * WN + ni * 16 + cl) * BK + ks * 32 + rh * 8];
            #pragma unroll
            for (int mi = 0; mi < FM; ++mi)
                #pragma unroll
                for (int ni = 0; ni < FN; ++ni)
                    acc[mi][ni] = __builtin_amdgcn_mfma_f32_16x16x32_bf16(
                        af[mi], bfr[ni], acc[mi][ni], 0, 0, 0);
        }
        __syncthreads();
    }

    // epilogue: C/D layout col=lane&15, row=(lane>>4)*4+j
    #pragma unroll
    for (int mi = 0; mi < FM; ++mi) {
        #pragma unroll
        for (int ni = 0; ni < FN; ++ni) {
            int gm = m0 + wm * WM + mi * 16 + rh * 4;
            int gn = n0 + wn * WN + ni * 16 + cl;
            float bsv = bias[gn];
            #pragma unroll
            for (int j = 0; j < 4; ++j) {
                float val = acc[mi][ni][j] + bsv;
                if (OUTBF)
                    ((unsigned short*)Cv)[(size_t)(gm + j) * N + gn] = f2bf(val);
                else
                    ((float*)Cv)[(size_t)(gm + j) * N + gn] = val;
            }
        }
    }
}

// ---------------------------------------------------------------------------
// Quantum statevector sim, register-resident.
// Amp index bits: [9:8]=wave, [7:2]=lane, [1:0]=reg slot. 4 amps/thread.
// Per layer: 2 reg gates + 6 shfl gates + one 4x4 cross-wave gate (LDS) +
// bit-linear CNOT permutation (LDS). 2 barriers/layer, double-buffered.
// ---------------------------------------------------------------------------
__global__ __launch_bounds__(256) void quantum_kernel(
    const unsigned short* __restrict__ xqb, const float* __restrict__ ang,
    const float* __restrict__ qw, const float* __restrict__ us,
    const float* __restrict__ mw, unsigned short* __restrict__ probs)
{
    __shared__ float2 buf0[QDIM];
    __shared__ float2 buf1[QDIM];
    __shared__ float lmat[DEPTH + 1][NQ][8];   // [4] = measurement gates
    __shared__ float red[4];

    const int tid = threadIdx.x;
    const int wv  = tid >> 6;
    const int ln  = tid & 63;
    const int wid = blockIdx.x;          // b*G+g
    const int g   = wid & 3;

    // ---- build all 50 fused gate matrices (data-independent carry chain) ----
    if (tid < (DEPTH + 1) * NQ) {
        const int l = tid / NQ;               // 0..4
        const int i = tid - l * NQ;
        float carry = 0.f;
        if (l > 0) {
            int pl = (l == DEPTH) ? DEPTH - 1 : l - 1;
            carry = qw[(((size_t)g * DEPTH + pl) * NQ + i) * 3 + 2];
        }
        float m0r,m0i,m1r,m1i,m2r,m2i,m3r,m3i;
        if (l < DEPTH) {
            int idx = (g * DEPTH + l) * NQ + i;
            float q0 = qw[(size_t)idx * 3 + 0], q1 = qw[(size_t)idx * 3 + 1];
            float beta = ang[(size_t)wid * NQ + i] * us[idx] + carry;
            float s0 = sinf(0.5f * q0), c0 = cosf(0.5f * q0);
            float s1 = sinf(0.5f * q1), c1 = cosf(0.5f * q1);
            // Q = Ry(q1)*Rx(q0)
            float p0r =  c1 * c0, p0i =  s1 * s0;
            float p1r = -s1 * c0, p1i = -c1 * s0;
            float p2r =  s1 * c0, p2i = -c1 * s0;
            float p3r =  c1 * c0, p3i = -s1 * s0;
            float cb = cosf(0.5f * beta), sb = sinf(0.5f * beta);
            m0r = p0r*cb + p1r*sb;  m0i = p0i*cb + p1i*sb;
            m1r = p1r*cb - p0r*sb;  m1i = p1i*cb - p0i*sb;
            m2r = p2r*cb + p3r*sb;  m2i = p2i*cb + p3i*sb;
            m3r = p3r*cb - p2r*sb;  m3i = p3i*cb - p2i*sb;
        } else {
            const float* q = mw + ((size_t)g * NQ + i) * 3;
            float th = q[0], ph = q[1], lm_ = q[2];
            float c = cosf(0.5f * th), s = sinf(0.5f * th);
            float epr = cosf(ph), epi = sinf(ph);
            float elr = cosf(lm_), eli = sinf(lm_);
            float u0r = c,        u0i = 0.f;
            float u1r = -elr * s, u1i = -eli * s;
            float u2r = epr * s,  u2i = epi * s;
            float u3r = (epr*elr - epi*eli) * c;
            float u3i = (epr*eli + epi*elr) * c;
            float cc = cosf(0.5f * carry), sc2 = sinf(0.5f * carry);
            m0r = u0r*cc + u1r*sc2;  m0i = u0i*cc + u1i*sc2;
            m1r = u1r*cc - u0r*sc2;  m1i = u1i*cc - u0i*sc2;
            m2r = u2r*cc + u3r*sc2;  m2i = u2i*cc + u3i*sc2;
            m3r = u3r*cc - u2r*sc2;  m3i = u3i*cc - u2i*sc2;
        }
        float* m = lmat[l][i];
        m[0]=m0r; m[1]=m0i; m[2]=m1r; m[3]=m1i;
        m[4]=m2r; m[5]=m2i; m[6]=m3r; m[7]=m3i;
    }

    // ---- load own 4 amps (bf16), block-wide norm ----
    float ar[4], ai[4];
    {
        ushort4 uv = ((const ushort4*)xqb)[(size_t)wid * 256 + tid];
        ar[0] = bf2f(uv.x); ar[1] = bf2f(uv.y);
        ar[2] = bf2f(uv.z); ar[3] = bf2f(uv.w);
    }
    float ss = ar[0]*ar[0] + ar[1]*ar[1] + ar[2]*ar[2] + ar[3]*ar[3];
    #pragma unroll
    for (int off = 32; off; off >>= 1) ss += __shfl_xor(ss, off, 64);
    if (ln == 0) red[wv] = ss;
    __syncthreads();     // also covers lmat writes
    {
        float scl = 1.f / (sqrtf(red[0] + red[1] + red[2] + red[3]) + EPSN);
        #pragma unroll
        for (int r = 0; r < 4; ++r) { ar[r] *= scl; ai[r] = 0.f; }
    }

    const int jb = tid << 2;

    // ---- fused gate set for one layer (matrices M[wire][8]) ----
    auto do_gates = [&](const float (*M)[8]) {
        // wire 9 -> amp bit 0: slots (0,1),(2,3)
        {
            const float* m = M[9];
            #pragma unroll
            for (int p = 0; p < 2; ++p) {
                const int e0 = 2*p, e1 = 2*p + 1;
                float a0r=ar[e0], a0i=ai[e0], a1r=ar[e1], a1i=ai[e1];
                ar[e0] = m[0]*a0r - m[1]*a0i + m[2]*a1r - m[3]*a1i;
                ai[e0] = m[0]*a0i + m[1]*a0r + m[2]*a1i + m[3]*a1r;
                ar[e1] = m[4]*a0r - m[5]*a0i + m[6]*a1r - m[7]*a1i;
                ai[e1] = m[4]*a0i + m[5]*a0r + m[6]*a1i + m[7]*a1r;
            }
        }
        // wire 8 -> amp bit 1: slots (0,2),(1,3)
        {
            const float* m = M[8];
            #pragma unroll
            for (int p = 0; p < 2; ++p) {
                const int e0 = p, e1 = p + 2;
                float a0r=ar[e0], a0i=ai[e0], a1r=ar[e1], a1i=ai[e1];
                ar[e0] = m[0]*a0r - m[1]*a0i + m[2]*a1r - m[3]*a1i;
                ai[e0] = m[0]*a0i + m[1]*a0r + m[2]*a1i + m[3]*a1r;
                ar[e1] = m[4]*a0r - m[5]*a0i + m[6]*a1r - m[7]*a1i;
                ai[e1] = m[4]*a0i + m[5]*a0r + m[6]*a1i + m[7]*a1r;
            }
        }
        // wires 7..2 -> lane bits 0..5: shfl_xor, no barrier
        #pragma unroll
        for (int i = 7; i >= 2; --i) {
            const float* m = M[i];
            const int bit = 7 - i;
            const int X = 1 << bit;
            const int side = (ln >> bit) & 1;
            float cAr = side ? m[6] : m[0], cAi = side ? m[7] : m[1];
            float cBr = side ? m[4] : m[2], cBi = side ? m[5] : m[3];
            #pragma unroll
            for (int r = 0; r < 4; ++r) {
                float tr = __shfl_xor(ar[r], X, 64);
                float ti = __shfl_xor(ai[r], X, 64);
                float nr = cAr*ar[r] - cAi*ai[r] + cBr*tr - cBi*ti;
                float ni = cAr*ai[r] + cAi*ar[r] + cBr*ti + cBi*tr;
                ar[r] = nr; ai[r] = ni;
            }
        }
        // wires 1,0 -> wave bits 8,9: combined 4x4 gate via LDS
        {
            ((float4*)&buf0[jb])[0] = make_float4(ar[0], ai[0], ar[1], ai[1]);
            ((float4*)&buf0[jb])[1] = make_float4(ar[2], ai[2], ar[3], ai[3]);
            const float* g0 = M[0];   // acts on bit 9
            const float* g1 = M[1];   // acts on bit 8
            const int b9 = wv >> 1, b8 = wv & 1;
            float Cr[4], Ci[4];
            #pragma unroll
            for (int wp = 0; wp < 4; ++wp) {
                const int b9p = wp >> 1, b8p = wp & 1;
                float e0r = g0[(b9*2 + b9p)*2], e0i = g0[(b9*2 + b9p)*2 + 1];
                float e1r = g1[(b8*2 + b8p)*2], e1i = g1[(b8*2 + b8p)*2 + 1];
                Cr[wp] = e0r*e1r - e0i*e1i;
                Ci[wp] = e0r*e1i + e0i*e1r;
            }
            __syncthreads();
            float nr[4] = {0,0,0,0}, ni[4] = {0,0,0,0};
            #pragma unroll
            for (int wp = 0; wp < 4; ++wp) {
                float4 p0 = ((const float4*)&buf0[(wp << 8) | (ln << 2)])[0];
                float4 p1 = ((const float4*)&buf0[(wp << 8) | (ln << 2)])[1];
                float br0 = p0.x, bi0 = p0.y, br1 = p0.z, bi1 = p0.w;
                float br2 = p1.x, bi2 = p1.y, br3 = p1.z, bi3 = p1.w;
                nr[0] += Cr[wp]*br0 - Ci[wp]*bi0;  ni[0] += Cr[wp]*bi0 + Ci[wp]*br0;
                nr[1] += Cr[wp]*br1 - Ci[wp]*bi1;  ni[1] += Cr[wp]*bi1 + Ci[wp]*br1;
                nr[2] += Cr[wp]*br2 - Ci[wp]*bi2;  ni[2] += Cr[wp]*bi2 + Ci[wp]*br2;
                nr[3] += Cr[wp]*br3 - Ci[wp]*bi3;  ni[3] += Cr[wp]*bi3 + Ci[wp]*br3;
            }
            #pragma unroll
            for (int r = 0; r < 4; ++r) { ar[r] = nr[r]; ai[r] = ni[r]; }
        }
    };

    // ---- CNOT-chain permutation: gather src k = (j^(j>>1)) ^ ((j&1)*0x300) ----
    auto do_perm = [&]() {
        ((float4*)&buf1[jb])[0] = make_float4(ar[0], ai[0], ar[1], ai[1]);
        ((float4*)&buf1[jb])[1] = make_float4(ar[2], ai[2], ar[3], ai[3]);
        __syncthreads();
        const int k0 = (jb ^ (jb >> 1)) & 1023;
        float2 s0 = buf1[k0];
        float2 s1 = buf1[k0 ^ 0x301];
        float2 s2 = buf1[k0 ^ 0x003];
        float2 s3 = buf1[k0 ^ 0x302];
        ar[0] = s0.x; ai[0] = s0.y;  ar[1] = s1.x; ai[1] = s1.y;
        ar[2] = s2.x; ai[2] = s2.y;  ar[3] = s3.x; ai[3] = s3.y;
    };

    #pragma unroll
    for (int l = 0; l < DEPTH; ++l) {
        do_gates(lmat[l]);
        do_perm();
    }
    do_gates(lmat[DEPTH]);   // measurement U3*Ry(carry)

    // ---- probs (bf16) ----
    {
        ushort4 o;
        o.x = f2bf(ar[0]*ar[0] + ai[0]*ai[0]);
        o.y = f2bf(ar[1]*ar[1] + ai[1]*ai[1]);
        o.z = f2bf(ar[2]*ar[2] + ai[2]*ai[2]);
        o.w = f2bf(ar[3]*ar[3] + ai[3]*ai[3]);
        ((ushort4*)(probs + (size_t)wid * QDIM))[tid] = o;
    }
}

// ---------------------------------------------------------------------------
extern "C" void kernel_launch(void* const* d_in, const int* in_sizes, int n_in,
                              void* d_out, int out_size, void* d_ws, size_t ws_size,
                              hipStream_t stream)
{
    const float* x          = (const float*)d_in[0];
    const float* inp_scale  = (const float*)d_in[1];
    const float* proj_in_w  = (const float*)d_in[2];
    const float* proj_in_b  = (const float*)d_in[3];
    const float* reup_w     = (const float*)d_in[4];
    const float* reup_b     = (const float*)d_in[5];
    const float* q_weights  = (const float*)d_in[6];
    const float* upl_scales = (const float*)d_in[7];
    const float* meas_w     = (const float*)d_in[8];
    const float* proj_out_w = (const float*)d_in[9];
    const float* proj_out_b = (const float*)d_in[10];
    float* out = (float*)d_out;

    char* ws = (char*)d_ws;
    unsigned short* xqb    = (unsigned short*)ws;                         // 8 MB
    unsigned short* probsb = (unsigned short*)(ws + ((size_t) 8 << 20));  // 8 MB
    unsigned short* wb1    = (unsigned short*)(ws + ((size_t)16 << 20));  // 8 MB
    unsigned short* wb2    = (unsigned short*)(ws + ((size_t)24 << 20));  // 8 MB
    unsigned short* xsb    = (unsigned short*)(ws + ((size_t)32 << 20));  // 2 MB
    float*          angb   = (float*)(ws + ((size_t)34 << 20));           // 160 KB

    // casts + reup in one launch
    prep_kernel<<<5632, 256, 0, stream>>>(x, inp_scale, proj_in_w, proj_out_w,
                                          reup_w, reup_b, xsb, wb1, wb2, angb);
    // xq(bf16) = xsb @ wb1^T + b   (1024 x 4096 x 1024)
    gemm_bt_bf16<64, 128, 32, true><<<dim3(32, 16), 256, 0, stream>>>(
        xsb, wb1, proj_in_b, xqb, BB, GG * QDIM, INN);
    // quantum sim -> probs (bf16)
    quantum_kernel<<<BB * GG, 256, 0, stream>>>(xqb, angb, q_weights,
                                                upl_scales, meas_w, probsb);
    // out = probs @ wb2^T + b   (1024 x 1024 x 4096)
    gemm_bt_bf16<64, 64, 64, false><<<dim3(16, 16), 256, 0, stream>>>(
        probsb, wb2, proj_out_b, out, BB, OUTN, GG * QDIM);
}

// Round 5
// 216.983 us; speedup vs baseline: 2.4056x; 1.1833x over previous
//
#include <hip/hip_runtime.h>
#include <hip/hip_bf16.h>
#include <math.h>

// Problem constants
#define BB    1024
#define INN   1024
#define OUTN  1024
#define NQ    10
#define GG    4
#define DEPTH 4
#define QDIM  1024   // 2^NQ
#define EPSN  1e-9f

typedef short  bf16x8 __attribute__((ext_vector_type(8)));
typedef float  f32x4  __attribute__((ext_vector_type(4)));

#define GLOAD_LDS16(gp, lp) __builtin_amdgcn_global_load_lds( \
    (__attribute__((address_space(1))) const void*)(gp),      \
    (__attribute__((address_space(3))) void*)(lp), 16, 0, 0)

__device__ __forceinline__ unsigned short f2bf(float f) {
    unsigned int u = __float_as_uint(f);
    u = (u + 0x7FFFu + ((u >> 16) & 1u)) >> 16;   // RNE, finite inputs
    return (unsigned short)u;
}
__device__ __forceinline__ float bf2f(unsigned short u) {
    return __uint_as_float(((unsigned int)u) << 16);
}

// DPP quad-perm xor1 / xor2 (VALU-pipe lane exchange)
template<int CTRL>
__device__ __forceinline__ float dppx(float x) {
    return __uint_as_float((unsigned)__builtin_amdgcn_update_dpp(
        0, (int)__float_as_uint(x), CTRL, 0xF, 0xF, true));
}

// complex 2x2 gate on register pairs (stride 1: (0,1),(2,3); stride 2: (0,2),(1,3))
__device__ __forceinline__ void rgate(float (&ar)[4], float (&ai)[4],
                                      const float* __restrict__ m, int stride)
{
    #pragma unroll
    for (int p = 0; p < 2; ++p) {
        const int e0 = (stride == 1) ? (p << 1) : p;
        const int e1 = e0 + stride;
        float a0r = ar[e0], a0i = ai[e0], a1r = ar[e1], a1i = ai[e1];
        ar[e0] = m[0]*a0r - m[1]*a0i + m[2]*a1r - m[3]*a1i;
        ai[e0] = m[0]*a0i + m[1]*a0r + m[2]*a1i + m[3]*a1r;
        ar[e1] = m[4]*a0r - m[5]*a0i + m[6]*a1r - m[7]*a1i;
        ai[e1] = m[4]*a0i + m[5]*a0r + m[6]*a1i + m[7]*a1r;
    }
}

// butterfly gate across lane-xor X
template<int X>
__device__ __forceinline__ void bfly(float (&ar)[4], float (&ai)[4],
                                     const float* __restrict__ m, int ln)
{
    const int side = (ln & X) ? 1 : 0;
    const float cAr = side ? m[6] : m[0], cAi = side ? m[7] : m[1];
    const float cBr = side ? m[4] : m[2], cBi = side ? m[5] : m[3];
    #pragma unroll
    for (int r = 0; r < 4; ++r) {
        float tr, ti;
        if (X == 1)      { tr = dppx<0xB1>(ar[r]); ti = dppx<0xB1>(ai[r]); }
        else if (X == 2) { tr = dppx<0x4E>(ar[r]); ti = dppx<0x4E>(ai[r]); }
        else             { tr = __shfl_xor(ar[r], X, 64); ti = __shfl_xor(ai[r], X, 64); }
        float nr = cAr*ar[r] - cAi*ai[r] + cBr*tr - cBi*ti;
        float ni = cAr*ai[r] + cAi*ar[r] + cBr*ti + cBi*tr;
        ar[r] = nr; ai[r] = ni;
    }
}

// ---------------------------------------------------------------------------
// Fused prep: [0,512): xsb = bf16(x*sc); [512,2560): wb1 = bf16(proj_in_w);
// [2560,4608): wb2 = bf16(proj_out_w); [4608,5632): reup angles.
// ---------------------------------------------------------------------------
__global__ __launch_bounds__(256) void prep_kernel(
    const float* __restrict__ x, const float* __restrict__ sc,
    const float* __restrict__ piw, const float* __restrict__ pow_,
    const float* __restrict__ rw, const float* __restrict__ rb,
    unsigned short* __restrict__ xsb, unsigned short* __restrict__ wb1,
    unsigned short* __restrict__ wb2, float* __restrict__ ang)
{
    const int bid = blockIdx.x;
    if (bid < 4608) {
        const float* src; unsigned short* dst; int i; bool scale = false;
        if (bid < 512)        { src = x;    dst = xsb; i = bid * 256 + threadIdx.x; scale = true; }
        else if (bid < 2560)  { src = piw;  dst = wb1; i = (bid - 512) * 256 + threadIdx.x; }
        else                  { src = pow_; dst = wb2; i = (bid - 2560) * 256 + threadIdx.x; }
        float4 a = ((const float4*)src)[2 * i];
        float4 b = ((const float4*)src)[2 * i + 1];
        if (scale) {
            int c4 = (2 * i) & 255;
            float4 s0 = ((const float4*)sc)[c4];
            float4 s1 = ((const float4*)sc)[c4 + 1];
            a.x *= s0.x; a.y *= s0.y; a.z *= s0.z; a.w *= s0.w;
            b.x *= s1.x; b.y *= s1.y; b.z *= s1.z; b.w *= s1.w;
        }
        ushort4 o0, o1;
        o0.x = f2bf(a.x); o0.y = f2bf(a.y); o0.z = f2bf(a.z); o0.w = f2bf(a.w);
        o1.x = f2bf(b.x); o1.y = f2bf(b.y); o1.z = f2bf(b.z); o1.w = f2bf(b.w);
        ((ushort4*)dst)[2 * i]     = o0;
        ((ushort4*)dst)[2 * i + 1] = o1;
    } else {
        const int b = bid - 4608;
        const int lane = threadIdx.x & 63;
        const int wv = threadIdx.x >> 6;
        const float* xrow = x + (size_t)b * INN;
        float xr[16];
        #pragma unroll
        for (int t = 0; t < 16; ++t) xr[t] = xrow[lane + 64 * t] * sc[lane + 64 * t];
        for (int j = wv; j < NQ * GG; j += 4) {
            const float* wrow = rw + (size_t)j * INN;
            float s = 0.f;
            #pragma unroll
            for (int t = 0; t < 16; ++t) s += xr[t] * wrow[lane + 64 * t];
            #pragma unroll
            for (int off = 32; off; off >>= 1) s += __shfl_xor(s, off, 64);
            if (lane == 0) {
                float a = tanhf(s + rb[j]) * 3.14159265358979323846f;
                int g = j / NQ, i = j % NQ;
                ang[((size_t)b * GG + g) * NQ + i] = a;
            }
        }
    }
}

// ---------------------------------------------------------------------------
// bf16 MFMA GEMM: C = A(M,K) * W(N,K)^T [+ bias]. Split-K via blockIdx.z:
// chunk k-range [z*KC, (z+1)*KC), partial written at Cv + z*M*N (fp32 path).
// ---------------------------------------------------------------------------
template<int BM, int BN, int BK, bool OUTBF>
__global__ __launch_bounds__(256) void gemm_bt_bf16(
    const unsigned short* __restrict__ A, const unsigned short* __restrict__ Bw,
    const float* __restrict__ bias, void* __restrict__ Cv,
    int M, int N, int K, int KC)
{
    constexpr int WM = BM / 2, WN = BN / 2;
    constexpr int FM = WM / 16, FN = WN / 16;
    constexpr int KS = BK / 32;
    constexpr int NA = (BM * BK) / 2048;
    constexpr int NB = (BN * BK) / 2048;

    __shared__ unsigned short As[BM * BK];
    __shared__ unsigned short Bs[BN * BK];

    const int tid  = threadIdx.x;
    const int lane = tid & 63;
    const int wave = tid >> 6;
    const int wm = wave >> 1, wn = wave & 1;
    const int m0 = blockIdx.y * BM;
    const int n0 = blockIdx.x * BN;
    const int k0 = blockIdx.z * KC;

    const int cl = lane & 15;
    const int rh = lane >> 4;

    f32x4 acc[FM][FN];
    #pragma unroll
    for (int i = 0; i < FM; ++i)
        #pragma unroll
        for (int j = 0; j < FN; ++j)
            acc[i][j] = (f32x4){0.f, 0.f, 0.f, 0.f};

    for (int kt = k0; kt < k0 + KC; kt += BK) {
        #pragma unroll
        for (int q = 0; q < NA; ++q) {
            int eo  = q * 2048 + tid * 8;
            int row = eo / BK, col = eo % BK;
            GLOAD_LDS16(A + (size_t)(m0 + row) * K + kt + col, &As[eo]);
        }
        #pragma unroll
        for (int q = 0; q < NB; ++q) {
            int eo  = q * 2048 + tid * 8;
            int row = eo / BK, col = eo % BK;
            GLOAD_LDS16(Bw + (size_t)(n0 + row) * K + kt + col, &Bs[eo]);
        }
        __syncthreads();

        #pragma unroll
        for (int ks = 0; ks < KS; ++ks) {
            bf16x8 af[FM], bfr[FN];
            #pragma unroll
            for (int mi = 0; mi < FM; ++mi)
                af[mi] = *(const bf16x8*)&As[(wm * WM + mi * 16 + cl) * BK + ks * 32 + rh * 8];
            #pragma unroll
            for (int ni = 0; ni < FN; ++ni)
                bfr[ni] = *(const bf16x8*)&Bs[(wn * WN + ni * 16 + cl) * BK + ks * 32 + rh * 8];
            #pragma unroll
            for (int mi = 0; mi < FM; ++mi)
                #pragma unroll
                for (int ni = 0; ni < FN; ++ni)
                    acc[mi][ni] = __builtin_amdgcn_mfma_f32_16x16x32_bf16(
                        af[mi], bfr[ni], acc[mi][ni], 0, 0, 0);
        }
        __syncthreads();
    }

    // epilogue: C/D layout col=lane&15, row=(lane>>4)*4+j
    #pragma unroll
    for (int mi = 0; mi < FM; ++mi) {
        #pragma unroll
        for (int ni = 0; ni < FN; ++ni) {
            int gm = m0 + wm * WM + mi * 16 + rh * 4;
            int gn = n0 + wn * WN + ni * 16 + cl;
            float bsv = bias ? bias[gn] : 0.f;
            #pragma unroll
            for (int j = 0; j < 4; ++j) {
                float val = acc[mi][ni][j] + bsv;
                if (OUTBF)
                    ((unsigned short*)Cv)[(size_t)(gm + j) * N + gn] = f2bf(val);
                else
                    ((float*)Cv)[(size_t)blockIdx.z * M * N + (size_t)(gm + j) * N + gn] = val;
            }
        }
    }
}

// out = p[0..MN) + p[MN..2MN) + bias  (float4)
__global__ __launch_bounds__(256) void reduce2_kernel(
    const float* __restrict__ p, const float* __restrict__ bias,
    float* __restrict__ out)
{
    int i = blockIdx.x * 256 + threadIdx.x;           // float4 index, 262144
    float4 a = ((const float4*)p)[i];
    float4 b = ((const float4*)p)[i + (1 << 18)];     // + M*N/4
    float4 bv = ((const float4*)bias)[i & 255];
    float4 o;
    o.x = a.x + b.x + bv.x; o.y = a.y + b.y + bv.y;
    o.z = a.z + b.z + bv.z; o.w = a.w + b.w + bv.w;
    ((float4*)out)[i] = o;
}

// ---------------------------------------------------------------------------
// Quantum statevector sim, register-resident.
// Amp bits: [9:8]=wave, [7:2]=lane, [1:0]=reg slot. 4 amps/thread.
// Per layer: 2 reg gates + 6 butterfly gates (DPP/shfl), then LDS transpose
// (bits 9:8 <-> 1:0, XOR-swizzled) -> 2 more reg gates -> LDS gather that
// composes transpose-back with the CNOT-chain permutation. 2 barriers/layer.
// ---------------------------------------------------------------------------
__global__ __launch_bounds__(256) void quantum_kernel(
    const unsigned short* __restrict__ xqb, const float* __restrict__ ang,
    const float* __restrict__ qw, const float* __restrict__ us,
    const float* __restrict__ mw, unsigned short* __restrict__ probs)
{
    __shared__ float2 bufA[QDIM];
    __shared__ float2 bufB[QDIM];
    __shared__ float lmat[DEPTH + 1][NQ][8];
    __shared__ float red[4];

    const int tid = threadIdx.x;
    const int wv  = tid >> 6;
    const int ln  = tid & 63;
    const int wid = blockIdx.x;          // b*G+g
    const int g   = wid & 3;

    // ---- build all 50 fused gate matrices ----
    if (tid < (DEPTH + 1) * NQ) {
        const int l = tid / NQ;
        const int i = tid - l * NQ;
        float carry = 0.f;
        if (l > 0) {
            int pl = (l == DEPTH) ? DEPTH - 1 : l - 1;
            carry = qw[(((size_t)g * DEPTH + pl) * NQ + i) * 3 + 2];
        }
        float m0r,m0i,m1r,m1i,m2r,m2i,m3r,m3i;
        if (l < DEPTH) {
            int idx = (g * DEPTH + l) * NQ + i;
            float q0 = qw[(size_t)idx * 3 + 0], q1 = qw[(size_t)idx * 3 + 1];
            float beta = ang[(size_t)wid * NQ + i] * us[idx] + carry;
            float s0 = sinf(0.5f * q0), c0 = cosf(0.5f * q0);
            float s1 = sinf(0.5f * q1), c1 = cosf(0.5f * q1);
            float p0r =  c1 * c0, p0i =  s1 * s0;
            float p1r = -s1 * c0, p1i = -c1 * s0;
            float p2r =  s1 * c0, p2i = -c1 * s0;
            float p3r =  c1 * c0, p3i = -s1 * s0;
            float cb = cosf(0.5f * beta), sb = sinf(0.5f * beta);
            m0r = p0r*cb + p1r*sb;  m0i = p0i*cb + p1i*sb;
            m1r = p1r*cb - p0r*sb;  m1i = p1i*cb - p0i*sb;
            m2r = p2r*cb + p3r*sb;  m2i = p2i*cb + p3i*sb;
            m3r = p3r*cb - p2r*sb;  m3i = p3i*cb - p2i*sb;
        } else {
            const float* q = mw + ((size_t)g * NQ + i) * 3;
            float th = q[0], ph = q[1], lm_ = q[2];
            float c = cosf(0.5f * th), s = sinf(0.5f * th);
            float epr = cosf(ph), epi = sinf(ph);
            float elr = cosf(lm_), eli = sinf(lm_);
            float u0r = c,        u0i = 0.f;
            float u1r = -elr * s, u1i = -eli * s;
            float u2r = epr * s,  u2i = epi * s;
            float u3r = (epr*elr - epi*eli) * c;
            float u3i = (epr*eli + epi*elr) * c;
            float cc = cosf(0.5f * carry), sc2 = sinf(0.5f * carry);
            m0r = u0r*cc + u1r*sc2;  m0i = u0i*cc + u1i*sc2;
            m1r = u1r*cc - u0r*sc2;  m1i = u1i*cc - u0i*sc2;
            m2r = u2r*cc + u3r*sc2;  m2i = u2i*cc + u3i*sc2;
            m3r = u3r*cc - u2r*sc2;  m3i = u3i*cc - u2i*sc2;
        }
        float* m = lmat[l][i];
        m[0]=m0r; m[1]=m0i; m[2]=m1r; m[3]=m1i;
        m[4]=m2r; m[5]=m2i; m[6]=m3r; m[7]=m3i;
    }

    // ---- load own 4 amps (bf16), block-wide norm ----
    float ar[4], ai[4];
    {
        ushort4 uv = ((const ushort4*)xqb)[(size_t)wid * 256 + tid];
        ar[0] = bf2f(uv.x); ar[1] = bf2f(uv.y);
        ar[2] = bf2f(uv.z); ar[3] = bf2f(uv.w);
    }
    float ss = ar[0]*ar[0] + ar[1]*ar[1] + ar[2]*ar[2] + ar[3]*ar[3];
    #pragma unroll
    for (int off = 32; off; off >>= 1) ss += __shfl_xor(ss, off, 64);
    if (ln == 0) red[wv] = ss;
    __syncthreads();     // also covers lmat writes
    {
        float scl = 1.f / (sqrtf(red[0] + red[1] + red[2] + red[3]) + EPSN);
        #pragma unroll
        for (int r = 0; r < 4; ++r) { ar[r] *= scl; ai[r] = 0.f; }
    }

    auto lo_gates = [&](const float (*M)[8]) {
        rgate(ar, ai, M[9], 1);    // bit0 = slot0
        rgate(ar, ai, M[8], 2);    // bit1 = slot1
        bfly<1>(ar, ai, M[7], ln);
        bfly<2>(ar, ai, M[6], ln);
        bfly<4>(ar, ai, M[5], ln);
        bfly<8>(ar, ai, M[4], ln);
        bfly<16>(ar, ai, M[3], ln);
        bfly<32>(ar, ai, M[2], ln);
    };
    // T1 transpose (bits 9:8 <-> 1:0) + wires 1,0 as register gates
    auto hi_gates = [&](const float (*M)[8]) {
        #pragma unroll
        for (int s = 0; s < 4; ++s) {
            int a = (wv << 8) | (ln << 2) | s;
            bufA[a ^ ((a >> 4) & 0xF)] = make_float2(ar[s], ai[s]);
        }
        __syncthreads();
        #pragma unroll
        for (int s = 0; s < 4; ++s) {
            int a = (s << 8) | (ln << 2) | wv;
            float2 v = bufA[a ^ ((a >> 4) & 0xF)];
            ar[s] = v.x; ai[s] = v.y;
        }
        rgate(ar, ai, M[1], 1);    // bit8 = slot0 (transposed)
        rgate(ar, ai, M[0], 2);    // bit9 = slot1 (transposed)
    };
    // transpose-back composed with CNOT-chain permutation
    auto perm_back = [&]() {
        #pragma unroll
        for (int s = 0; s < 4; ++s) {
            int a = (s << 8) | (ln << 2) | wv;      // amp index held in slot s
            bufB[a ^ ((a >> 5) & 0xF)] = make_float2(ar[s], ai[s]);
        }
        __syncthreads();
        #pragma unroll
        for (int s = 0; s < 4; ++s) {
            int j = (wv << 8) | (ln << 2) | s;
            int k = (j ^ (j >> 1)) ^ ((j & 1) ? 0x300 : 0);
            float2 v = bufB[k ^ ((k >> 5) & 0xF)];
            ar[s] = v.x; ai[s] = v.y;
        }
    };

    #pragma unroll
    for (int l = 0; l < DEPTH; ++l) {
        lo_gates(lmat[l]);
        hi_gates(lmat[l]);
        perm_back();
    }
    lo_gates(lmat[DEPTH]);
    hi_gates(lmat[DEPTH]);

    // ---- probs: square in transposed layout, LDS pass back to standard ----
    #pragma unroll
    for (int s = 0; s < 4; ++s) {
        int a = (s << 8) | (ln << 2) | wv;
        bufB[a ^ ((a >> 5) & 0xF)].x = ar[s]*ar[s] + ai[s]*ai[s];
    }
    __syncthreads();
    {
        ushort4 o;
        int j0 = tid << 2;
        int a0 = (j0 + 0), a1 = (j0 + 1), a2 = (j0 + 2), a3 = (j0 + 3);
        o.x = f2bf(bufB[a0 ^ ((a0 >> 5) & 0xF)].x);
        o.y = f2bf(bufB[a1 ^ ((a1 >> 5) & 0xF)].x);
        o.z = f2bf(bufB[a2 ^ ((a2 >> 5) & 0xF)].x);
        o.w = f2bf(bufB[a3 ^ ((a3 >> 5) & 0xF)].x);
        ((ushort4*)(probs + (size_t)wid * QDIM))[tid] = o;
    }
}

// ---------------------------------------------------------------------------
extern "C" void kernel_launch(void* const* d_in, const int* in_sizes, int n_in,
                              void* d_out, int out_size, void* d_ws, size_t ws_size,
                              hipStream_t stream)
{
    const float* x          = (const float*)d_in[0];
    const float* inp_scale  = (const float*)d_in[1];
    const float* proj_in_w  = (const float*)d_in[2];
    const float* proj_in_b  = (const float*)d_in[3];
    const float* reup_w     = (const float*)d_in[4];
    const float* reup_b     = (const float*)d_in[5];
    const float* q_weights  = (const float*)d_in[6];
    const float* upl_scales = (const float*)d_in[7];
    const float* meas_w     = (const float*)d_in[8];
    const float* proj_out_w = (const float*)d_in[9];
    const float* proj_out_b = (const float*)d_in[10];
    float* out = (float*)d_out;

    char* ws = (char*)d_ws;
    unsigned short* xqb    = (unsigned short*)ws;                         // 8 MB (dead after quantum)
    float*          cpart  = (float*)ws;                                  // 8 MB (2x fp32 partials, reuses xqb)
    unsigned short* probsb = (unsigned short*)(ws + ((size_t) 8 << 20));  // 8 MB
    unsigned short* wb1    = (unsigned short*)(ws + ((size_t)16 << 20));  // 8 MB
    unsigned short* wb2    = (unsigned short*)(ws + ((size_t)24 << 20));  // 8 MB
    unsigned short* xsb    = (unsigned short*)(ws + ((size_t)32 << 20));  // 2 MB
    float*          angb   = (float*)(ws + ((size_t)34 << 20));           // 160 KB

    // casts + reup in one launch
    prep_kernel<<<5632, 256, 0, stream>>>(x, inp_scale, proj_in_w, proj_out_w,
                                          reup_w, reup_b, xsb, wb1, wb2, angb);
    // xq(bf16) = xsb @ wb1^T + b   (1024 x 4096 x 1024)
    gemm_bt_bf16<64, 128, 32, true><<<dim3(32, 16, 1), 256, 0, stream>>>(
        xsb, wb1, proj_in_b, xqb, BB, GG * QDIM, INN, INN);
    // quantum sim -> probs (bf16)
    quantum_kernel<<<BB * GG, 256, 0, stream>>>(xqb, angb, q_weights,
                                                upl_scales, meas_w, probsb);
    // out_partial[z] = probs @ wb2^T  (split-K=2: 1024 x 1024 x 2048 each)
    gemm_bt_bf16<64, 64, 64, false><<<dim3(16, 16, 2), 256, 0, stream>>>(
        probsb, wb2, nullptr, cpart, BB, OUTN, GG * QDIM, GG * QDIM / 2);
    // out = partial0 + partial1 + bias
    reduce2_kernel<<<1024, 256, 0, stream>>>(cpart, proj_out_b, out);
}

// Round 6
// 204.008 us; speedup vs baseline: 2.5586x; 1.0636x over previous
//
#include <hip/hip_runtime.h>
#include <hip/hip_bf16.h>
#include <math.h>

// Problem constants
#define BB    1024
#define INN   1024
#define OUTN  1024
#define NQ    10
#define GG    4
#define DEPTH 4
#define QDIM  1024   // 2^NQ
#define EPSN  1e-9f

typedef short  bf16x8 __attribute__((ext_vector_type(8)));
typedef float  f32x4  __attribute__((ext_vector_type(4)));

#define GLOAD_LDS16(gp, lp) __builtin_amdgcn_global_load_lds( \
    (__attribute__((address_space(1))) const void*)(gp),      \
    (__attribute__((address_space(3))) void*)(lp), 16, 0, 0)

__device__ __forceinline__ unsigned short f2bf(float f) {
    unsigned int u = __float_as_uint(f);
    u = (u + 0x7FFFu + ((u >> 16) & 1u)) >> 16;   // RNE, finite inputs
    return (unsigned short)u;
}
__device__ __forceinline__ float bf2f(unsigned short u) {
    return __uint_as_float(((unsigned int)u) << 16);
}

// DPP quad-perm xor1 / xor2 (VALU-pipe lane exchange)
template<int CTRL>
__device__ __forceinline__ float dppx(float x) {
    return __uint_as_float((unsigned)__builtin_amdgcn_update_dpp(
        0, (int)__float_as_uint(x), CTRL, 0xF, 0xF, true));
}

// complex 2x2 gate on register pairs
__device__ __forceinline__ void rgate(float (&ar)[4], float (&ai)[4],
                                      const float* __restrict__ m, int stride)
{
    #pragma unroll
    for (int p = 0; p < 2; ++p) {
        const int e0 = (stride == 1) ? (p << 1) : p;
        const int e1 = e0 + stride;
        float a0r = ar[e0], a0i = ai[e0], a1r = ar[e1], a1i = ai[e1];
        ar[e0] = m[0]*a0r - m[1]*a0i + m[2]*a1r - m[3]*a1i;
        ai[e0] = m[0]*a0i + m[1]*a0r + m[2]*a1i + m[3]*a1r;
        ar[e1] = m[4]*a0r - m[5]*a0i + m[6]*a1r - m[7]*a1i;
        ai[e1] = m[4]*a0i + m[5]*a0r + m[6]*a1i + m[7]*a1r;
    }
}

// butterfly gate across lane-xor X
template<int X>
__device__ __forceinline__ void bfly(float (&ar)[4], float (&ai)[4],
                                     const float* __restrict__ m, int ln)
{
    const int side = (ln & X) ? 1 : 0;
    const float cAr = side ? m[6] : m[0], cAi = side ? m[7] : m[1];
    const float cBr = side ? m[4] : m[2], cBi = side ? m[5] : m[3];
    #pragma unroll
    for (int r = 0; r < 4; ++r) {
        float tr, ti;
        if (X == 1)      { tr = dppx<0xB1>(ar[r]); ti = dppx<0xB1>(ai[r]); }
        else if (X == 2) { tr = dppx<0x4E>(ar[r]); ti = dppx<0x4E>(ai[r]); }
        else             { tr = __shfl_xor(ar[r], X, 64); ti = __shfl_xor(ai[r], X, 64); }
        float nr = cAr*ar[r] - cAi*ai[r] + cBr*tr - cBi*ti;
        float ni = cAr*ai[r] + cAi*ar[r] + cBr*ti + cBi*tr;
        ar[r] = nr; ai[r] = ni;
    }
}

// ---------------------------------------------------------------------------
// Fused prep: [0,512): xsb = bf16(x*sc); [512,2560): wb1 = bf16(proj_in_w);
// [2560,4608): wb2 = bf16(proj_out_w); [4608,5632): reup angles.
// ---------------------------------------------------------------------------
__global__ __launch_bounds__(256) void prep_kernel(
    const float* __restrict__ x, const float* __restrict__ sc,
    const float* __restrict__ piw, const float* __restrict__ pow_,
    const float* __restrict__ rw, const float* __restrict__ rb,
    unsigned short* __restrict__ xsb, unsigned short* __restrict__ wb1,
    unsigned short* __restrict__ wb2, float* __restrict__ ang)
{
    const int bid = blockIdx.x;
    if (bid < 4608) {
        const float* src; unsigned short* dst; int i; bool scale = false;
        if (bid < 512)        { src = x;    dst = xsb; i = bid * 256 + threadIdx.x; scale = true; }
        else if (bid < 2560)  { src = piw;  dst = wb1; i = (bid - 512) * 256 + threadIdx.x; }
        else                  { src = pow_; dst = wb2; i = (bid - 2560) * 256 + threadIdx.x; }
        float4 a = ((const float4*)src)[2 * i];
        float4 b = ((const float4*)src)[2 * i + 1];
        if (scale) {
            int c4 = (2 * i) & 255;
            float4 s0 = ((const float4*)sc)[c4];
            float4 s1 = ((const float4*)sc)[c4 + 1];
            a.x *= s0.x; a.y *= s0.y; a.z *= s0.z; a.w *= s0.w;
            b.x *= s1.x; b.y *= s1.y; b.z *= s1.z; b.w *= s1.w;
        }
        ushort4 o0, o1;
        o0.x = f2bf(a.x); o0.y = f2bf(a.y); o0.z = f2bf(a.z); o0.w = f2bf(a.w);
        o1.x = f2bf(b.x); o1.y = f2bf(b.y); o1.z = f2bf(b.z); o1.w = f2bf(b.w);
        ((ushort4*)dst)[2 * i]     = o0;
        ((ushort4*)dst)[2 * i + 1] = o1;
    } else {
        const int b = bid - 4608;
        const int lane = threadIdx.x & 63;
        const int wv = threadIdx.x >> 6;
        const float* xrow = x + (size_t)b * INN;
        float xr[16];
        #pragma unroll
        for (int t = 0; t < 16; ++t) xr[t] = xrow[lane + 64 * t] * sc[lane + 64 * t];
        for (int j = wv; j < NQ * GG; j += 4) {
            const float* wrow = rw + (size_t)j * INN;
            float s = 0.f;
            #pragma unroll
            for (int t = 0; t < 16; ++t) s += xr[t] * wrow[lane + 64 * t];
            #pragma unroll
            for (int off = 32; off; off >>= 1) s += __shfl_xor(s, off, 64);
            if (lane == 0) {
                float a = tanhf(s + rb[j]) * 3.14159265358979323846f;
                int g = j / NQ, i = j % NQ;
                ang[((size_t)b * GG + g) * NQ + i] = a;
            }
        }
    }
}

// ---------------------------------------------------------------------------
// bf16 MFMA GEMM: C = A(M,K) * W(N,K)^T [+ bias]. BK=128, XOR-swizzled LDS
// (linear dest + pre-swizzled global source: 16B block gb = pb ^ (row&7)).
// Split-K via blockIdx.z: k-range [z*KC,(z+1)*KC); fp32 partials at hole
// offsets (z&1)*M*N + (z>>1)*4*M*N floats (see kernel_launch layout).
// ---------------------------------------------------------------------------
template<int BM, int BN, int BK, bool OUTBF>
__global__ __launch_bounds__(256) void gemm_bt_bf16(
    const unsigned short* __restrict__ A, const unsigned short* __restrict__ Bw,
    const float* __restrict__ bias, void* __restrict__ Cv,
    int M, int N, int K, int KC)
{
    static_assert(BK == 128, "swizzle assumes BK=128");
    constexpr int WM = BM / 2, WN = BN / 2;
    constexpr int FM = WM / 16, FN = WN / 16;
    constexpr int KS = BK / 32;
    constexpr int NA = (BM * BK) / 2048;
    constexpr int NB = (BN * BK) / 2048;

    __shared__ unsigned short As[BM * BK];
    __shared__ unsigned short Bs[BN * BK];

    const int tid  = threadIdx.x;
    const int lane = tid & 63;
    const int wave = tid >> 6;
    const int wm = wave >> 1, wn = wave & 1;
    const int m0 = blockIdx.y * BM;
    const int n0 = blockIdx.x * BN;
    const int k0 = blockIdx.z * KC;

    const int cl = lane & 15;
    const int rh = lane >> 4;

    f32x4 acc[FM][FN];
    #pragma unroll
    for (int i = 0; i < FM; ++i)
        #pragma unroll
        for (int j = 0; j < FN; ++j)
            acc[i][j] = (f32x4){0.f, 0.f, 0.f, 0.f};

    for (int kt = k0; kt < k0 + KC; kt += BK) {
        #pragma unroll
        for (int q = 0; q < NA; ++q) {
            int eo  = q * 2048 + tid * 8;
            int row = eo >> 7;                 // eo / BK
            int pb  = (eo & 127) >> 3;         // 16B block within row
            int gb  = pb ^ (row & 7);          // pre-swizzled global block
            GLOAD_LDS16(A + (size_t)(m0 + row) * K + kt + gb * 8, &As[eo]);
        }
        #pragma unroll
        for (int q = 0; q < NB; ++q) {
            int eo  = q * 2048 + tid * 8;
            int row = eo >> 7;
            int pb  = (eo & 127) >> 3;
            int gb  = pb ^ (row & 7);
            GLOAD_LDS16(Bw + (size_t)(n0 + row) * K + kt + gb * 8, &Bs[eo]);
        }
        __syncthreads();

        #pragma unroll
        for (int ks = 0; ks < KS; ++ks) {
            bf16x8 af[FM], bfr[FN];
            #pragma unroll
            for (int mi = 0; mi < FM; ++mi) {
                int row = wm * WM + mi * 16 + cl;
                int pb  = (ks * 4 + rh) ^ (row & 7);
                af[mi] = *(const bf16x8*)&As[row * BK + pb * 8];
            }
            #pragma unroll
            for (int ni = 0; ni < FN; ++ni) {
                int row = wn * WN + ni * 16 + cl;
                int pb  = (ks * 4 + rh) ^ (row & 7);
                bfr[ni] = *(const bf16x8*)&Bs[row * BK + pb * 8];
            }
            #pragma unroll
            for (int mi = 0; mi < FM; ++mi)
                #pragma unroll
                for (int ni = 0; ni < FN; ++ni)
                    acc[mi][ni] = __builtin_amdgcn_mfma_f32_16x16x32_bf16(
                        af[mi], bfr[ni], acc[mi][ni], 0, 0, 0);
        }
        __syncthreads();
    }

    // epilogue: C/D layout col=lane&15, row=(lane>>4)*4+j
    const size_t pofs = OUTBF ? 0 :
        ((size_t)(blockIdx.z & 1) + ((size_t)(blockIdx.z >> 1) << 2)) * ((size_t)M * N);
    #pragma unroll
    for (int mi = 0; mi < FM; ++mi) {
        #pragma unroll
        for (int ni = 0; ni < FN; ++ni) {
            int gm = m0 + wm * WM + mi * 16 + rh * 4;
            int gn = n0 + wn * WN + ni * 16 + cl;
            float bsv = bias ? bias[gn] : 0.f;
            #pragma unroll
            for (int j = 0; j < 4; ++j) {
                float val = acc[mi][ni][j] + bsv;
                if (OUTBF)
                    ((unsigned short*)Cv)[(size_t)(gm + j) * N + gn] = f2bf(val);
                else
                    ((float*)Cv)[pofs + (size_t)(gm + j) * N + gn] = val;
            }
        }
    }
}

// out = p0 + p1 + p2 + p3 + bias; partials at float4 offsets 0, 1<<18, 1<<20, (1<<20)+(1<<18)
__global__ __launch_bounds__(256) void reduce4_kernel(
    const float* __restrict__ p, const float* __restrict__ bias,
    float* __restrict__ out)
{
    int i = blockIdx.x * 256 + threadIdx.x;           // float4 index, 262144
    float4 a = ((const float4*)p)[i];
    float4 b = ((const float4*)p)[i + (1 << 18)];
    float4 c = ((const float4*)p)[i + (1 << 20)];
    float4 d = ((const float4*)p)[i + (1 << 20) + (1 << 18)];
    float4 bv = ((const float4*)bias)[i & 255];
    float4 o;
    o.x = a.x + b.x + c.x + d.x + bv.x;
    o.y = a.y + b.y + c.y + d.y + bv.y;
    o.z = a.z + b.z + c.z + d.z + bv.z;
    o.w = a.w + b.w + c.w + d.w + bv.w;
    ((float4*)out)[i] = o;
}

// ---------------------------------------------------------------------------
// Quantum statevector sim, register-resident (unchanged from R5).
// ---------------------------------------------------------------------------
__global__ __launch_bounds__(256) void quantum_kernel(
    const unsigned short* __restrict__ xqb, const float* __restrict__ ang,
    const float* __restrict__ qw, const float* __restrict__ us,
    const float* __restrict__ mw, unsigned short* __restrict__ probs)
{
    __shared__ float2 bufA[QDIM];
    __shared__ float2 bufB[QDIM];
    __shared__ float lmat[DEPTH + 1][NQ][8];
    __shared__ float red[4];

    const int tid = threadIdx.x;
    const int wv  = tid >> 6;
    const int ln  = tid & 63;
    const int wid = blockIdx.x;          // b*G+g
    const int g   = wid & 3;

    if (tid < (DEPTH + 1) * NQ) {
        const int l = tid / NQ;
        const int i = tid - l * NQ;
        float carry = 0.f;
        if (l > 0) {
            int pl = (l == DEPTH) ? DEPTH - 1 : l - 1;
            carry = qw[(((size_t)g * DEPTH + pl) * NQ + i) * 3 + 2];
        }
        float m0r,m0i,m1r,m1i,m2r,m2i,m3r,m3i;
        if (l < DEPTH) {
            int idx = (g * DEPTH + l) * NQ + i;
            float q0 = qw[(size_t)idx * 3 + 0], q1 = qw[(size_t)idx * 3 + 1];
            float beta = ang[(size_t)wid * NQ + i] * us[idx] + carry;
            float s0 = sinf(0.5f * q0), c0 = cosf(0.5f * q0);
            float s1 = sinf(0.5f * q1), c1 = cosf(0.5f * q1);
            float p0r =  c1 * c0, p0i =  s1 * s0;
            float p1r = -s1 * c0, p1i = -c1 * s0;
            float p2r =  s1 * c0, p2i = -c1 * s0;
            float p3r =  c1 * c0, p3i = -s1 * s0;
            float cb = cosf(0.5f * beta), sb = sinf(0.5f * beta);
            m0r = p0r*cb + p1r*sb;  m0i = p0i*cb + p1i*sb;
            m1r = p1r*cb - p0r*sb;  m1i = p1i*cb - p0i*sb;
            m2r = p2r*cb + p3r*sb;  m2i = p2i*cb + p3i*sb;
            m3r = p3r*cb - p2r*sb;  m3i = p3i*cb - p2i*sb;
        } else {
            const float* q = mw + ((size_t)g * NQ + i) * 3;
            float th = q[0], ph = q[1], lm_ = q[2];
            float c = cosf(0.5f * th), s = sinf(0.5f * th);
            float epr = cosf(ph), epi = sinf(ph);
            float elr = cosf(lm_), eli = sinf(lm_);
            float u0r = c,        u0i = 0.f;
            float u1r = -elr * s, u1i = -eli * s;
            float u2r = epr * s,  u2i = epi * s;
            float u3r = (epr*elr - epi*eli) * c;
            float u3i = (epr*eli + epi*elr) * c;
            float cc = cosf(0.5f * carry), sc2 = sinf(0.5f * carry);
            m0r = u0r*cc + u1r*sc2;  m0i = u0i*cc + u1i*sc2;
            m1r = u1r*cc - u0r*sc2;  m1i = u1i*cc - u0i*sc2;
            m2r = u2r*cc + u3r*sc2;  m2i = u2i*cc + u3i*sc2;
            m3r = u3r*cc - u2r*sc2;  m3i = u3i*cc - u2i*sc2;
        }
        float* m = lmat[l][i];
        m[0]=m0r; m[1]=m0i; m[2]=m1r; m[3]=m1i;
        m[4]=m2r; m[5]=m2i; m[6]=m3r; m[7]=m3i;
    }

    float ar[4], ai[4];
    {
        ushort4 uv = ((const ushort4*)xqb)[(size_t)wid * 256 + tid];
        ar[0] = bf2f(uv.x); ar[1] = bf2f(uv.y);
        ar[2] = bf2f(uv.z); ar[3] = bf2f(uv.w);
    }
    float ss = ar[0]*ar[0] + ar[1]*ar[1] + ar[2]*ar[2] + ar[3]*ar[3];
    #pragma unroll
    for (int off = 32; off; off >>= 1) ss += __shfl_xor(ss, off, 64);
    if (ln == 0) red[wv] = ss;
    __syncthreads();     // also covers lmat writes
    {
        float scl = 1.f / (sqrtf(red[0] + red[1] + red[2] + red[3]) + EPSN);
        #pragma unroll
        for (int r = 0; r < 4; ++r) { ar[r] *= scl; ai[r] = 0.f; }
    }

    auto lo_gates = [&](const float (*M)[8]) {
        rgate(ar, ai, M[9], 1);
        rgate(ar, ai, M[8], 2);
        bfly<1>(ar, ai, M[7], ln);
        bfly<2>(ar, ai, M[6], ln);
        bfly<4>(ar, ai, M[5], ln);
        bfly<8>(ar, ai, M[4], ln);
        bfly<16>(ar, ai, M[3], ln);
        bfly<32>(ar, ai, M[2], ln);
    };
    auto hi_gates = [&](const float (*M)[8]) {
        #pragma unroll
        for (int s = 0; s < 4; ++s) {
            int a = (wv << 8) | (ln << 2) | s;
            bufA[a ^ ((a >> 4) & 0xF)] = make_float2(ar[s], ai[s]);
        }
        __syncthreads();
        #pragma unroll
        for (int s = 0; s < 4; ++s) {
            int a = (s << 8) | (ln << 2) | wv;
            float2 v = bufA[a ^ ((a >> 4) & 0xF)];
            ar[s] = v.x; ai[s] = v.y;
        }
        rgate(ar, ai, M[1], 1);
        rgate(ar, ai, M[0], 2);
    };
    auto perm_back = [&]() {
        #pragma unroll
        for (int s = 0; s < 4; ++s) {
            int a = (s << 8) | (ln << 2) | wv;
            bufB[a ^ ((a >> 5) & 0xF)] = make_float2(ar[s], ai[s]);
        }
        __syncthreads();
        #pragma unroll
        for (int s = 0; s < 4; ++s) {
            int j = (wv << 8) | (ln << 2) | s;
            int k = (j ^ (j >> 1)) ^ ((j & 1) ? 0x300 : 0);
            float2 v = bufB[k ^ ((k >> 5) & 0xF)];
            ar[s] = v.x; ai[s] = v.y;
        }
    };

    #pragma unroll
    for (int l = 0; l < DEPTH; ++l) {
        lo_gates(lmat[l]);
        hi_gates(lmat[l]);
        perm_back();
    }
    lo_gates(lmat[DEPTH]);
    hi_gates(lmat[DEPTH]);

    #pragma unroll
    for (int s = 0; s < 4; ++s) {
        int a = (s << 8) | (ln << 2) | wv;
        bufB[a ^ ((a >> 5) & 0xF)].x = ar[s]*ar[s] + ai[s]*ai[s];
    }
    __syncthreads();
    {
        ushort4 o;
        int j0 = tid << 2;
        int a0 = (j0 + 0), a1 = (j0 + 1), a2 = (j0 + 2), a3 = (j0 + 3);
        o.x = f2bf(bufB[a0 ^ ((a0 >> 5) & 0xF)].x);
        o.y = f2bf(bufB[a1 ^ ((a1 >> 5) & 0xF)].x);
        o.z = f2bf(bufB[a2 ^ ((a2 >> 5) & 0xF)].x);
        o.w = f2bf(bufB[a3 ^ ((a3 >> 5) & 0xF)].x);
        ((ushort4*)(probs + (size_t)wid * QDIM))[tid] = o;
    }
}

// ---------------------------------------------------------------------------
// ws layout (34.2 MB, stream-ordered reuse):
//   [ 0, 8)MB : xqb (gemm1 out, quantum in)   -> cpart z=0,1 (gemm2 out)
//   [ 8,16)MB : probsb? NO -> see below
//   [16,24)MB : wb1 (gemm1 B)                 -> probsb (quantum out, gemm2 A)
//   [24,32)MB : wb2 (gemm2 B)
//   [32,34)MB : xsb
//   34MB+     : angb
//   cpart z=2,3 live at [16,24)?? -> probsb occupies it. Partials hole map:
//   z=0 -> ws+0MB, z=1 -> ws+4MB, z=2 -> ws+16MB?? probsb conflict.
//   RESOLUTION: probsb stays at [8,16)MB; cpart = {0,4} and {16,20}MB uses
//   xqb (dead) and wb1 (dead after gemm1). probsb untouched.
// ---------------------------------------------------------------------------
extern "C" void kernel_launch(void* const* d_in, const int* in_sizes, int n_in,
                              void* d_out, int out_size, void* d_ws, size_t ws_size,
                              hipStream_t stream)
{
    const float* x          = (const float*)d_in[0];
    const float* inp_scale  = (const float*)d_in[1];
    const float* proj_in_w  = (const float*)d_in[2];
    const float* proj_in_b  = (const float*)d_in[3];
    const float* reup_w     = (const float*)d_in[4];
    const float* reup_b     = (const float*)d_in[5];
    const float* q_weights  = (const float*)d_in[6];
    const float* upl_scales = (const float*)d_in[7];
    const float* meas_w     = (const float*)d_in[8];
    const float* proj_out_w = (const float*)d_in[9];
    const float* proj_out_b = (const float*)d_in[10];
    float* out = (float*)d_out;

    char* ws = (char*)d_ws;
    unsigned short* xqb    = (unsigned short*)ws;                         // 8 MB, dead after quantum
    float*          cpart  = (float*)ws;                                  // partials z0@0MB z1@4MB z2@16MB z3@20MB
    unsigned short* probsb = (unsigned short*)(ws + ((size_t) 8 << 20));  // 8 MB
    unsigned short* wb1    = (unsigned short*)(ws + ((size_t)16 << 20));  // 8 MB, dead after gemm1
    unsigned short* wb2    = (unsigned short*)(ws + ((size_t)24 << 20));  // 8 MB
    unsigned short* xsb    = (unsigned short*)(ws + ((size_t)32 << 20));  // 2 MB
    float*          angb   = (float*)(ws + ((size_t)34 << 20));           // 160 KB

    // casts + reup in one launch
    prep_kernel<<<5632, 256, 0, stream>>>(x, inp_scale, proj_in_w, proj_out_w,
                                          reup_w, reup_b, xsb, wb1, wb2, angb);
    // xq(bf16) = xsb @ wb1^T + b   (1024 x 4096 x 1024), BK=128
    gemm_bt_bf16<64, 128, 128, true><<<dim3(32, 16, 1), 256, 0, stream>>>(
        xsb, wb1, proj_in_b, xqb, BB, GG * QDIM, INN, INN);
    // quantum sim -> probs (bf16)
    quantum_kernel<<<BB * GG, 256, 0, stream>>>(xqb, angb, q_weights,
                                                upl_scales, meas_w, probsb);
    // partial[z] = probs @ wb2^T  (split-K=4: 1024 x 1024 x 1024 each)
    gemm_bt_bf16<64, 64, 128, false><<<dim3(16, 16, 4), 256, 0, stream>>>(
        probsb, wb2, nullptr, cpart, BB, OUTN, GG * QDIM, GG * QDIM / 4);
    // out = sum partials + bias
    reduce4_kernel<<<1024, 256, 0, stream>>>(cpart, proj_out_b, out);
}